// Round 5
// baseline (311.316 us; speedup 1.0000x reference)
//
#include <hip/hip_runtime.h>
#include <hip/hip_bf16.h>

// MultiHeadAttention: B=4, T=2048, D=1024, H=16, dk=64, causal.
// cast->bf16 | fused QKV gemm (256x256, ring-4 BK=32 sub-tiles) | flash attn (QBLK=128) | out proj.

typedef __attribute__((ext_vector_type(8))) short bf16x8;   // 8 bf16 = 4 VGPRs (A/B frag)
typedef __attribute__((ext_vector_type(4))) float f32x4;    // C/D frag

__device__ __forceinline__ unsigned short f2b(float x) {
  __hip_bfloat16 h = __float2bfloat16(x);
  return __builtin_bit_cast(unsigned short, h);
}

// async global->LDS, 16B per lane. LDS dst = wave-uniform base + lane*16.
__device__ __forceinline__ void load_lds16(const void* g, void* l) {
  __builtin_amdgcn_global_load_lds((__attribute__((address_space(1))) void*)g,
                                   (__attribute__((address_space(3))) void*)l,
                                   16, 0, 0);
}

// ---------------- fused cast kernel: x (1048576 chunks) then Wq|Wk|Wv|Wo (131072 each) ----
__global__ void cast_kernel(const float* __restrict__ x,
                            const float* __restrict__ w0, const float* __restrict__ w1,
                            const float* __restrict__ w2, const float* __restrict__ w3,
                            unsigned short* __restrict__ xb, unsigned short* __restrict__ wb) {
  int i = blockIdx.x * 256 + threadIdx.x;
  const float* src;
  unsigned short* dst;
  int c;
  if (i < 1048576) {
    src = x; dst = xb; c = i;
  } else {
    int cw = i - 1048576;
    int wi = cw >> 17;           // which weight
    c = cw & 131071;
    src = (wi == 0) ? w0 : (wi == 1) ? w1 : (wi == 2) ? w2 : w3;
    dst = wb + ((size_t)wi << 20);
  }
  const float4* s4 = (const float4*)src;
  float4 a = s4[2 * c], b = s4[2 * c + 1];
  union { unsigned short u[8]; uint4 v; } r;
  r.u[0] = f2b(a.x); r.u[1] = f2b(a.y); r.u[2] = f2b(a.z); r.u[3] = f2b(a.w);
  r.u[4] = f2b(b.x); r.u[5] = f2b(b.y); r.u[6] = f2b(b.z); r.u[7] = f2b(b.w);
  ((uint4*)dst)[c] = r.v;
}

// ---------------- fused QKV GEMM: 256x256 tile, ring-4 of BK=32 sub-tiles ----------------
// M=8192, N=3072, K=1024. 512 thr = 8 waves (2M x 4N), per-wave output 128x64.
// R4 post-mortem: 64x64/wave = 0.5 ds_reads/MFMA -> LDS pipe time ~= MFMA pipe time,
// barrier lockstep alternates them -> 24.5% MfmaUtil pinned across 3 schedule variants.
// Fix = intensity: 128x64/wave (m201 geometry, 62% proven) = 0.375 reads/MFMA; per sub-tile
// per CU: 96 b128 (~770cyc) < MFMA 1030cyc/SIMD. Ring-4 32KB sub-tiles (128KB LDS): stage
// t+3 while computing t -> issue-to-wait ~2.5 sub-tiles > HBM latency; counted vmcnt(8),
// never 0 mid-loop (R3's fault: vmcnt(0) at ~500cyc distance stalled every tile).
// ONE barrier per sub-tile (staging never targets a live buffer). Grid (32,12)=384 blocks,
// bijective XCD swizzle (n-major within XCD -> B-panel L2 reuse); 1.5-round tail accepted.
__launch_bounds__(512, 2)
__global__ void gemm_qkv(const unsigned short* __restrict__ A,
                         const unsigned short* __restrict__ Bw,
                         unsigned short* __restrict__ Cout) {
  __shared__ unsigned short As[4][256 * 32];   // 4 x 16 KB
  __shared__ unsigned short Bs[4][256 * 32];   // 4 x 16 KB  (total 128 KB)

  const int tid = threadIdx.x;
  const int lane = tid & 63;
  const int w = tid >> 6;          // 0..7
  const int quad = lane >> 4;
  const int l15 = lane & 15;

  // XCD swizzle: flat id -> xcd = flat&7 (round-robin dispatch). Give each XCD 48
  // consecutive wgids, n-major (32 same-n blocks contiguous -> B-panel stays in its L2).
  const int flat = blockIdx.x + (blockIdx.y << 5);        // 0..383
  const int wg = ((flat & 7) * 48) + (flat >> 3);
  const int mx = wg & 31, ny = wg >> 5;
  const int m0 = mx * 256;
  const int n0 = ny * 256;
  const int wm = (w >> 2) * 128;   // 2 m-halves
  const int wn = (w & 3) * 64;     // 4 n-quads

  // stage sub-tile s (k in [s*32, s*32+32)) into buf s&3. 2 passes/operand, 4 glds total.
  // LDS linear dst; global src pre-swizzled: chunk c of row holds global chunk c^((row>>1)&3)
  // -> ds_read of a 16-lane column slice lands 2-way (free) on banks.
  auto stageA = [&](int s, int pass) {
    int buf = s & 3;
    int chunk = pass * 512 + tid;
    int row = chunk >> 2;
    int c = chunk & 3;
    int sc = c ^ ((row >> 1) & 3);
    load_lds16(A + (size_t)(m0 + row) * 1024 + s * 32 + sc * 8,
               &As[buf][(pass * 512 + (w << 6)) << 3]);
  };
  auto stageB = [&](int s, int pass) {
    int buf = s & 3;
    int chunk = pass * 512 + tid;
    int row = chunk >> 2;
    int c = chunk & 3;
    int sc = c ^ ((row >> 1) & 3);
    load_lds16(Bw + (size_t)(n0 + row) * 1024 + s * 32 + sc * 8,
               &Bs[buf][(pass * 512 + (w << 6)) << 3]);
  };

  const f32x4 z4 = {0.f, 0.f, 0.f, 0.f};
  f32x4 acc[8][4];                 // [m: wm + (i>>2)*64 + (i&3)*16][n: wn + j*16]
#pragma unroll
  for (int i = 0; i < 8; ++i)
#pragma unroll
    for (int j = 0; j < 4; ++j) acc[i][j] = z4;

  // prologue: stage sub-tiles 0,1,2 (12 glds); wait t0 complete (8 newest still flying).
#pragma unroll
  for (int s = 0; s < 3; ++s) {
    stageA(s, 0); stageA(s, 1); stageB(s, 0); stageB(s, 1);
  }
  asm volatile("s_waitcnt vmcnt(8)" ::: "memory");
  __builtin_amdgcn_s_barrier();
  __builtin_amdgcn_sched_barrier(0);

  for (int t = 0; t < 32; ++t) {
    const int buf = t & 3;
    const bool st = (t < 29);
    const int s3 = t + 3;

    bf16x8 a0[4], a1[4], bfr[4];

    // ---- half 0: read A-m0[4] + B[4]; stage A(t+3); 16 MFMA ----
#pragma unroll
    for (int i = 0; i < 4; ++i) {
      int rowA = wm + i * 16 + l15;
      a0[i] = *(const bf16x8*)&As[buf][rowA * 32 + ((quad ^ ((rowA >> 1) & 3)) << 3)];
    }
#pragma unroll
    for (int j = 0; j < 4; ++j) {
      int rowB = wn + j * 16 + l15;
      bfr[j] = *(const bf16x8*)&Bs[buf][rowB * 32 + ((quad ^ ((rowB >> 1) & 3)) << 3)];
    }
    if (st) { stageA(s3, 0); stageA(s3, 1); }
    __builtin_amdgcn_s_setprio(1);
#pragma unroll
    for (int i = 0; i < 4; ++i)
#pragma unroll
      for (int j = 0; j < 4; ++j)
        acc[i][j] = __builtin_amdgcn_mfma_f32_16x16x32_bf16(a0[i], bfr[j], acc[i][j], 0, 0, 0);
    __builtin_amdgcn_s_setprio(0);

    // ---- half 1: read A-m1[4]; stage B(t+3); 16 MFMA (B frags reused) ----
#pragma unroll
    for (int i = 0; i < 4; ++i) {
      int rowA = wm + 64 + i * 16 + l15;
      a1[i] = *(const bf16x8*)&As[buf][rowA * 32 + ((quad ^ ((rowA >> 1) & 3)) << 3)];
    }
    if (st) { stageB(s3, 0); stageB(s3, 1); }
    __builtin_amdgcn_s_setprio(1);
#pragma unroll
    for (int i = 0; i < 4; ++i)
#pragma unroll
      for (int j = 0; j < 4; ++j)
        acc[4 + i][j] = __builtin_amdgcn_mfma_f32_16x16x32_bf16(a1[i], bfr[j], acc[4 + i][j], 0, 0, 0);
    __builtin_amdgcn_s_setprio(0);

    // ---- sub-tile boundary: ensure t+1 landed. Counted; drains only in the tail. ----
    if (t < 29) {
      asm volatile("s_waitcnt vmcnt(8)" ::: "memory");
    } else if (t == 29) {
      asm volatile("s_waitcnt vmcnt(4)" ::: "memory");
    } else if (t == 30) {
      asm volatile("s_waitcnt vmcnt(0)" ::: "memory");
    }
    __builtin_amdgcn_s_barrier();
    __builtin_amdgcn_sched_barrier(0);
  }

  // epilogue. C/D layout: col = lane&15, row = quad*4 + reg.
  const int seg = n0 >> 10;  // uniform per block (256 | 1024)
#pragma unroll
  for (int i = 0; i < 8; ++i) {
#pragma unroll
    for (int j = 0; j < 4; ++j) {
#pragma unroll
      for (int r = 0; r < 4; ++r) {
        int m = m0 + wm + (i >> 2) * 64 + (i & 3) * 16 + quad * 4 + r;
        int n = n0 + wn + j * 16 + l15;
        int nn = n & 1023;
        float v = acc[i][j][r];
        if (seg == 0) {
          Cout[(size_t)m * 1024 + nn] = f2b(v);
        } else if (seg == 1) {
          (Cout + 8388608)[(size_t)m * 1024 + nn] = f2b(v);
        } else {
          int b = m >> 11, tq = m & 2047, hh = nn >> 6, d = nn & 63;
          (Cout + 16777216)[(((size_t)((b * 16 + hh) * 64 + d)) << 11) + tq] = f2b(v);
        }
      }
    }
  }
}

// ---------------- out-proj GEMM: 128x64 tile, grid (64,16)=1024 blocks, bias folded ------
__launch_bounds__(256)
__global__ void gemm_proj(const unsigned short* __restrict__ A,
                          const unsigned short* __restrict__ Bw,
                          const float* __restrict__ bias,
                          float* __restrict__ out) {
  __shared__ unsigned short At[128 * 64];   // 16 KB
  __shared__ unsigned short Bt[64 * 64];    // 8 KB

  const int tid = threadIdx.x;
  const int lane = tid & 63;
  const int w = tid >> 6;
  const int quad = lane >> 4;
  const int l15 = lane & 15;
  const int m0 = blockIdx.x * 128;
  const int n0 = blockIdx.y * 64;
  const int wm = w * 32;

  const f32x4 z4 = {0.f, 0.f, 0.f, 0.f};
  f32x4 acc[2][4];
#pragma unroll
  for (int i = 0; i < 2; ++i)
#pragma unroll
    for (int j = 0; j < 4; ++j) acc[i][j] = z4;

  for (int kt = 0; kt < 1024; kt += 64) {
    __syncthreads();
#pragma unroll
    for (int c = 0; c < 4; ++c) {
      int chunk = c * 256 + tid;
      int row = chunk >> 3;
      int scol = (chunk & 7) ^ (row & 7);
      load_lds16(A + (size_t)(m0 + row) * 1024 + kt + scol * 8,
                 &At[((c * 256 + (w << 6)) << 3)]);
    }
#pragma unroll
    for (int c = 0; c < 2; ++c) {
      int chunk = c * 256 + tid;
      int row = chunk >> 3;
      int scol = (chunk & 7) ^ (row & 7);
      load_lds16(Bw + (size_t)(n0 + row) * 1024 + kt + scol * 8,
                 &Bt[((c * 256 + (w << 6)) << 3)]);
    }
    __syncthreads();
#pragma unroll
    for (int ks = 0; ks < 2; ++ks) {
      bf16x8 af[2], bf[4];
#pragma unroll
      for (int i = 0; i < 2; ++i) {
        int rowA = wm + i * 16 + l15;
        af[i] = *(const bf16x8*)&At[rowA * 64 + (((ks * 4 + quad) ^ (rowA & 7)) << 3)];
      }
#pragma unroll
      for (int j = 0; j < 4; ++j) {
        int rowB = j * 16 + l15;
        bf[j] = *(const bf16x8*)&Bt[rowB * 64 + (((ks * 4 + quad) ^ (rowB & 7)) << 3)];
      }
#pragma unroll
      for (int i = 0; i < 2; ++i)
#pragma unroll
        for (int j = 0; j < 4; ++j)
          acc[i][j] = __builtin_amdgcn_mfma_f32_16x16x32_bf16(af[i], bf[j], acc[i][j], 0, 0, 0);
    }
  }

#pragma unroll
  for (int i = 0; i < 2; ++i)
#pragma unroll
    for (int j = 0; j < 4; ++j) {
      int n = n0 + j * 16 + l15;
      float bv = bias[n];
#pragma unroll
      for (int r = 0; r < 4; ++r) {
        int m = m0 + wm + i * 16 + quad * 4 + r;
        out[(size_t)m * 1024 + n] = acc[i][j][r] + bv;
      }
    }
}

// ---------------- causal flash attention (S^T form, fixed-max softmax, QBLK=128) ---------
// grid (bh=64, pp=8), 256 thr. Flat block id = bh + 64*pp -> XCD = bh%8: all 8 pp-blocks of
// a head land on ONE XCD; per-XCD K/V working set = 8 heads x 512 KB = 4 MB = L2.
// Block handles 128-row q-tiles {pp, 15-pp}: uniform 34 k-tile iters. Each wave owns 32 q
// rows (two 16-row groups): K/V frags read from LDS ONCE feed BOTH groups.
// Fixed max M0=11: p = 2^(raw*SC - 11); the 2^-11 factor cancels in O/l.
__launch_bounds__(256)
__global__ void attn_kernel(const unsigned short* __restrict__ Q,
                            const unsigned short* __restrict__ K,
                            const unsigned short* __restrict__ VT,
                            unsigned short* __restrict__ ctx) {
  __shared__ unsigned short Kt[2][64 * 64];   // 2 x 8 KB
  __shared__ unsigned short Vt[2][64 * 64];   // 2 x 8 KB
  __shared__ unsigned short Pt[128 * 64];     // 16 KB: P^T rows = block q rows (wave-local)

  const int tid = threadIdx.x;
  const int lane = tid & 63;
  const int w = tid >> 6;
  const int quad = lane >> 4;
  const int l15 = lane & 15;
  const int bh = blockIdx.x;            // head-major: keeps a head's K/V on one XCD
  const int pp = blockIdx.y;
  const int b = bh >> 4, h = bh & 15;

  const unsigned short* Kg = K + ((size_t)(b * 2048)) * 1024 + h * 64;  // +t*1024
  const unsigned short* Vg = VT + ((size_t)bh * 64) * 2048;             // +d*2048+t

  const float SC = 0.1803368801f;  // (1/sqrt(64)) * log2(e)
  const float M0 = 11.0f;          // fixed max in log2 domain

  for (int tt = 0; tt < 2; ++tt) {
    const int qt = tt ? (15 - pp) : pp;  // 128-row q-tile index
    const int qb = qt * 128;
    const int jn = 2 * qt + 2;           // # of 64-wide k-tiles

    // Q frags: 2 row-groups x 2 k-steps
    bf16x8 qa[2][2];
#pragma unroll
    for (int g = 0; g < 2; ++g) {
      const unsigned short* qbase =
          Q + ((size_t)(b * 2048 + qb + w * 32 + g * 16 + l15)) * 1024 + h * 64;
      qa[g][0] = *(const bf16x8*)(qbase + quad * 8);
      qa[g][1] = *(const bf16x8*)(qbase + 32 + quad * 8);
    }

    const f32x4 z4 = {0.f, 0.f, 0.f, 0.f};
    f32x4 o[2][4];
#pragma unroll
    for (int g = 0; g < 2; ++g)
#pragma unroll
      for (int nt = 0; nt < 4; ++nt) o[g][nt] = z4;
    float lrow[2] = {0.f, 0.f};

    if (tt) __syncthreads();  // protect LDS buffers from previous tile's readers

    // stage j=0 into buffer 0
#pragma unroll
    for (int c = 0; c < 2; ++c) {
      int chunk = c * 256 + tid;
      int row = chunk >> 3;
      int scol = (chunk & 7) ^ (row & 7);
      load_lds16(Kg + (size_t)row * 1024 + scol * 8, &Kt[0][((c * 256 + (w << 6)) << 3)]);
      load_lds16(Vg + ((size_t)row << 11) + scol * 8, &Vt[0][((c * 256 + (w << 6)) << 3)]);
    }

    int cur = 0;
    for (int j = 0; j < jn; ++j) {
      const int j0 = j * 64;
      __syncthreads();  // stage(j) drained; prior-iter LDS reads done

      if (j + 1 < jn) {  // prefetch j+1 into alternate buffer; overlaps compute below
        const int nj0 = j0 + 64;
#pragma unroll
        for (int c = 0; c < 2; ++c) {
          int chunk = c * 256 + tid;
          int row = chunk >> 3;
          int scol = (chunk & 7) ^ (row & 7);
          load_lds16(Kg + (size_t)(nj0 + row) * 1024 + scol * 8,
                     &Kt[cur ^ 1][((c * 256 + (w << 6)) << 3)]);
          load_lds16(Vg + ((size_t)row << 11) + nj0 + scol * 8,
                     &Vt[cur ^ 1][((c * 256 + (w << 6)) << 3)]);
        }
      }

      // S^T = K Q^T for both groups: kf read ONCE, 2 MFMA per read.
      f32x4 st[2][4];
#pragma unroll
      for (int g = 0; g < 2; ++g)
#pragma unroll
        for (int nt = 0; nt < 4; ++nt) st[g][nt] = z4;
#pragma unroll
      for (int ks = 0; ks < 2; ++ks) {
#pragma unroll
        for (int nt = 0; nt < 4; ++nt) {
          int rowK = nt * 16 + l15;
          bf16x8 kf = *(const bf16x8*)&Kt[cur][rowK * 64 + (((ks * 4 + quad) ^ (rowK & 7)) << 3)];
          st[0][nt] = __builtin_amdgcn_mfma_f32_16x16x32_bf16(kf, qa[0][ks], st[0][nt], 0, 0, 0);
          st[1][nt] = __builtin_amdgcn_mfma_f32_16x16x32_bf16(kf, qa[1][ks], st[1][nt], 0, 0, 0);
        }
      }

      // softmax: p = 2^(raw*SC - M0); causal mask; per-iter butterfly sum. Per group.
#pragma unroll
      for (int g = 0; g < 2; ++g) {
        const int qmin = qb + w * 32 + g * 16;
        const bool dg = (j0 + 63 > qmin);
        const int q = qmin + l15;
        float sum = 0.f;
#pragma unroll
        for (int nt = 0; nt < 4; ++nt) {
#pragma unroll
          for (int r = 0; r < 4; ++r) {
            float e = fmaf(st[g][nt][r], SC, -M0);
            if (dg) {
              int kpos = j0 + nt * 16 + quad * 4 + r;
              if (kpos > q) e = -1e30f;
            }
            float pv = __builtin_amdgcn_exp2f(e);
            st[g][nt][r] = pv;
            sum += pv;
          }
        }
        sum += __shfl_xor(sum, 16);
        sum += __shfl_xor(sum, 32);
        lrow[g] += sum;
      }

      // P^T -> Pt[qrow][kpos] (ushort4, swizzled by q&15), wave-local region (32 rows)
#pragma unroll
      for (int g = 0; g < 2; ++g) {
        const int qrow = w * 32 + g * 16 + l15;
#pragma unroll
        for (int nt = 0; nt < 4; ++nt) {
          ushort4 pk;
          pk.x = f2b(st[g][nt][0]); pk.y = f2b(st[g][nt][1]);
          pk.z = f2b(st[g][nt][2]); pk.w = f2b(st[g][nt][3]);
          int chunk = nt * 4 + quad;  // kpos chunk (4 shorts)
          *(ushort4*)&Pt[qrow * 64 + ((chunk ^ l15) << 2)] = pk;
        }
      }
      // no barrier: P region is wave-local

      // O += P V : vb read ONCE per (ks,nt), 2 MFMA per read.
#pragma unroll
      for (int ks = 0; ks < 2; ++ks) {
        int c0 = ks * 8 + quad * 2;
        union { ushort4 hh[2]; bf16x8 v; } pu[2];
#pragma unroll
        for (int g = 0; g < 2; ++g) {
          const int qrow = w * 32 + g * 16 + l15;
          pu[g].hh[0] = *(const ushort4*)&Pt[qrow * 64 + ((c0 ^ l15) << 2)];
          pu[g].hh[1] = *(const ushort4*)&Pt[qrow * 64 + (((c0 + 1) ^ l15) << 2)];
        }
#pragma unroll
        for (int nt = 0; nt < 4; ++nt) {
          int rowV = nt * 16 + l15;
          bf16x8 vb = *(const bf16x8*)&Vt[cur][rowV * 64 + (((ks * 4 + quad) ^ (rowV & 7)) << 3)];
          o[0][nt] = __builtin_amdgcn_mfma_f32_16x16x32_bf16(pu[0].v, vb, o[0][nt], 0, 0, 0);
          o[1][nt] = __builtin_amdgcn_mfma_f32_16x16x32_bf16(pu[1].v, vb, o[1][nt], 0, 0, 0);
        }
      }
      cur ^= 1;
    }

    // epilogue: ctx[b, q, h*64+d] bf16. O C-layout: row=q_local=quad*4+r, col=d=l15.
#pragma unroll
    for (int g = 0; g < 2; ++g) {
      float lf[4];
#pragma unroll
      for (int r = 0; r < 4; ++r) lf[r] = 1.f / __shfl(lrow[g], quad * 4 + r);
#pragma unroll
      for (int nt = 0; nt < 4; ++nt) {
#pragma unroll
        for (int r = 0; r < 4; ++r) {
          int q = qb + w * 32 + g * 16 + quad * 4 + r;
          int dcol = nt * 16 + l15;
          ctx[((size_t)(b * 2048 + q)) * 1024 + h * 64 + dcol] = f2b(o[g][nt][r] * lf[r]);
        }
      }
    }
  }
}

// ---------------- launcher ----------------
extern "C" void kernel_launch(void* const* d_in, const int* in_sizes, int n_in,
                              void* d_out, int out_size, void* d_ws, size_t ws_size,
                              hipStream_t stream) {
  const float* x  = (const float*)d_in[0];
  // d_in[1] = mask (causal, deterministic) — unused
  const float* Wq = (const float*)d_in[2];
  const float* Wk = (const float*)d_in[3];
  const float* Wv = (const float*)d_in[4];
  const float* Wo = (const float*)d_in[5];
  const float* bo = (const float*)d_in[6];
  float* out = (float*)d_out;

  unsigned short* xb  = (unsigned short*)d_ws;      // 8.4M elems (16 MB)
  unsigned short* wb  = xb + 8388608;               // 4 x 1M elems (8 MB) — Wq,Wk,Wv,Wo contiguous
  unsigned short* Qb  = wb + 4 * 1048576;           // Q; K at +8388608, VT at +16777216
  unsigned short* Kb  = Qb + 8388608;
  unsigned short* VTb = Kb + 8388608;
  unsigned short* ctxb = xb;                        // overlay: x dead after QKV

  cast_kernel<<<6144, 256, 0, stream>>>(x, Wq, Wk, Wv, Wo, xb, wb);

  // fused QKV: N=3072 (Wq|Wk|Wv contiguous in wb), 256x256 tiles, ring-4 BK=32 sub-tiles
  gemm_qkv<<<dim3(32, 12), 512, 0, stream>>>(xb, wb, Qb);

  // attn: grid (bh, pp) — head-major for XCD/L2 locality; 128-row q-tile pairs {pp, 15-pp}
  attn_kernel<<<dim3(64, 8), 256, 0, stream>>>(Qb, Kb, VTb, ctxb);

  // out proj: 128x64 tiles, 1024 blocks, bias folded, plain fp32 store
  gemm_proj<<<dim3(64, 16), 256, 0, stream>>>(ctxb, wb + 3 * 1048576, bo, out);
}

// Round 6
// 280.535 us; speedup vs baseline: 1.1097x; 1.1097x over previous
//
#include <hip/hip_runtime.h>
#include <hip/hip_bf16.h>

// MultiHeadAttention: B=4, T=2048, D=1024, H=16, dk=64, causal.
// cast->bf16 | fused QKV gemm (256x128 ring-3, 1 barrier/tile) | flash attn (QBLK=128) | out proj (ring-3).

typedef __attribute__((ext_vector_type(8))) short bf16x8;   // 8 bf16 = 4 VGPRs (A/B frag)
typedef __attribute__((ext_vector_type(4))) float f32x4;    // C/D frag

__device__ __forceinline__ unsigned short f2b(float x) {
  __hip_bfloat16 h = __float2bfloat16(x);
  return __builtin_bit_cast(unsigned short, h);
}

// async global->LDS, 16B per lane. LDS dst = wave-uniform base + lane*16.
__device__ __forceinline__ void load_lds16(const void* g, void* l) {
  __builtin_amdgcn_global_load_lds((__attribute__((address_space(1))) void*)g,
                                   (__attribute__((address_space(3))) void*)l,
                                   16, 0, 0);
}

// ---------------- fused cast kernel: x (1048576 chunks) then Wq|Wk|Wv|Wo (131072 each) ----
__global__ void cast_kernel(const float* __restrict__ x,
                            const float* __restrict__ w0, const float* __restrict__ w1,
                            const float* __restrict__ w2, const float* __restrict__ w3,
                            unsigned short* __restrict__ xb, unsigned short* __restrict__ wb) {
  int i = blockIdx.x * 256 + threadIdx.x;
  const float* src;
  unsigned short* dst;
  int c;
  if (i < 1048576) {
    src = x; dst = xb; c = i;
  } else {
    int cw = i - 1048576;
    int wi = cw >> 17;           // which weight
    c = cw & 131071;
    src = (wi == 0) ? w0 : (wi == 1) ? w1 : (wi == 2) ? w2 : w3;
    dst = wb + ((size_t)wi << 20);
  }
  const float4* s4 = (const float4*)src;
  float4 a = s4[2 * c], b = s4[2 * c + 1];
  union { unsigned short u[8]; uint4 v; } r;
  r.u[0] = f2b(a.x); r.u[1] = f2b(a.y); r.u[2] = f2b(a.z); r.u[3] = f2b(a.w);
  r.u[4] = f2b(b.x); r.u[5] = f2b(b.y); r.u[6] = f2b(b.z); r.u[7] = f2b(b.w);
  ((uint4*)dst)[c] = r.v;
}

// ---------------- fused QKV GEMM: 256x128 tile, BK=64, ring-of-3 LDS, 1 barrier/tile -----
// M=8192, N=3072, K=1024. 512 thr = 8 waves of 64x64. Grid 32x24 = 768 = 3*256 (no tail).
// R5 post-mortem: XCD swizzle doubled FETCH (L2 working set > 4MB/XCD) + 1.5-round tail ->
// revert to default mapping. R4 post-mortem: 4 barriers/tile lockstep the LDS-read bursts
// against MFMA clusters across waves -> 24.5% MfmaUtil pinned. R6: ONE barrier per K-tile.
// Ring-3 invariant makes this safe: a wave's ds_reads of buf complete before its barrier
// (compiler lgkm-waits precede the MFMAs that use them, all before the barrier in program
// order), so staging into that buf one tile later never races. Waves drift within a tile ->
// one wave's LDS reads overlap another's MFMAs (m114 co-schedule). vmcnt(6) counted, never
// 0 mid-loop (prefetch distance = full tile > HBM latency).
__launch_bounds__(512, 2)
__global__ void gemm_qkv(const unsigned short* __restrict__ A,
                         const unsigned short* __restrict__ Bw,
                         unsigned short* __restrict__ Cout) {
  __shared__ unsigned short At[3][256 * 64];   // 3 x 32 KB
  __shared__ unsigned short Bt[3][128 * 64];   // 3 x 16 KB  (total 144 KB)

  const int tid = threadIdx.x;
  const int lane = tid & 63;
  const int w = tid >> 6;          // 0..7
  const int quad = lane >> 4;
  const int l15 = lane & 15;
  const int m0 = blockIdx.x * 256;
  const int n0 = blockIdx.y * 128;
  const int wm = (w & 3) * 64;     // wave m-offset (4 m-waves)
  const int wn = (w >> 2) * 64;    // wave n-offset (2 n-waves)

  // stage helpers: LDS chunk (row, col8) holds global col (col8 ^ (row&7)) -> conflict-free.
  auto stageA = [&](int buf, int kt, int c) {
    int chunk = c * 512 + tid;
    int row = chunk >> 3;
    int scol = (chunk & 7) ^ (row & 7);
    load_lds16(A + (size_t)(m0 + row) * 1024 + kt + scol * 8,
               &At[buf][(c * 512 + (w << 6)) << 3]);
  };
  auto stageB = [&](int buf, int kt, int c) {
    int chunk = c * 512 + tid;
    int row = chunk >> 3;
    int scol = (chunk & 7) ^ (row & 7);
    load_lds16(Bw + (size_t)(n0 + row) * 1024 + kt + scol * 8,
               &Bt[buf][(c * 512 + (w << 6)) << 3]);
  };

  const f32x4 z4 = {0.f, 0.f, 0.f, 0.f};
  f32x4 acc[4][4];
#pragma unroll
  for (int i = 0; i < 4; ++i)
#pragma unroll
    for (int j = 0; j < 4; ++j) acc[i][j] = z4;

  // prologue: stage tiles 0 and 1 (6 instrs each); wait t0 complete (t1 in flight).
#pragma unroll
  for (int c = 0; c < 4; ++c) stageA(0, 0, c);
#pragma unroll
  for (int c = 0; c < 2; ++c) stageB(0, 0, c);
#pragma unroll
  for (int c = 0; c < 4; ++c) stageA(1, 64, c);
#pragma unroll
  for (int c = 0; c < 2; ++c) stageB(1, 64, c);
  asm volatile("s_waitcnt vmcnt(6)" ::: "memory");
  __builtin_amdgcn_s_barrier();
  __builtin_amdgcn_sched_barrier(0);

  int buf = 0;
  for (int t = 0; t < 16; ++t) {
    const int sbuf = (buf >= 1) ? buf - 1 : 2;   // (t+2)%3
    const int skt = (t + 2) * 64;
    const bool st = (t < 14);

    // ---- k-slice 0: 8 reads (4A+4B) | 3 stage | 16 MFMA (no barrier) ----
    {
      bf16x8 a0[4], b0[4];
#pragma unroll
      for (int i = 0; i < 4; ++i) {
        int rowA = wm + i * 16 + l15;
        a0[i] = *(const bf16x8*)&At[buf][rowA * 64 + ((quad ^ (rowA & 7)) << 3)];
      }
#pragma unroll
      for (int j = 0; j < 4; ++j) {
        int rowB = wn + j * 16 + l15;
        b0[j] = *(const bf16x8*)&Bt[buf][rowB * 64 + ((quad ^ (rowB & 7)) << 3)];
      }
      if (st) { stageA(sbuf, skt, 0); stageA(sbuf, skt, 1); stageA(sbuf, skt, 2); }
      __builtin_amdgcn_s_setprio(1);
#pragma unroll
      for (int i = 0; i < 4; ++i)
#pragma unroll
        for (int j = 0; j < 4; ++j)
          acc[i][j] = __builtin_amdgcn_mfma_f32_16x16x32_bf16(a0[i], b0[j], acc[i][j], 0, 0, 0);
      __builtin_amdgcn_s_setprio(0);
    }

    // ---- k-slice 1: 8 reads | 3 stage | 16 MFMA | counted vmcnt | ONE barrier ----
    {
      bf16x8 a1[4], b1[4];
#pragma unroll
      for (int i = 0; i < 4; ++i) {
        int rowA = wm + i * 16 + l15;
        a1[i] = *(const bf16x8*)&At[buf][rowA * 64 + (((4 + quad) ^ (rowA & 7)) << 3)];
      }
#pragma unroll
      for (int j = 0; j < 4; ++j) {
        int rowB = wn + j * 16 + l15;
        b1[j] = *(const bf16x8*)&Bt[buf][rowB * 64 + (((4 + quad) ^ (rowB & 7)) << 3)];
      }
      if (st) { stageA(sbuf, skt, 3); stageB(sbuf, skt, 0); stageB(sbuf, skt, 1); }
      __builtin_amdgcn_s_setprio(1);
#pragma unroll
      for (int i = 0; i < 4; ++i)
#pragma unroll
        for (int j = 0; j < 4; ++j)
          acc[i][j] = __builtin_amdgcn_mfma_f32_16x16x32_bf16(a1[i], b1[j], acc[i][j], 0, 0, 0);
      __builtin_amdgcn_s_setprio(0);
      // boundary: tile t+1 landed (issued a full tile ago). Counted, never 0 mid-loop.
      if (t < 14) {
        asm volatile("s_waitcnt vmcnt(6)" ::: "memory");
      } else if (t == 14) {
        asm volatile("s_waitcnt vmcnt(0)" ::: "memory");
      }
      __builtin_amdgcn_s_barrier();
      __builtin_amdgcn_sched_barrier(0);
    }

    buf = (buf < 2) ? buf + 1 : 0;
  }

  // epilogue. C/D layout: col = lane&15, row = quad*4 + reg.
  const int seg = n0 >> 10;  // uniform per block
#pragma unroll
  for (int i = 0; i < 4; ++i) {
#pragma unroll
    for (int j = 0; j < 4; ++j) {
#pragma unroll
      for (int r = 0; r < 4; ++r) {
        int m = m0 + wm + i * 16 + quad * 4 + r;
        int n = n0 + wn + j * 16 + l15;
        int nn = n & 1023;
        float v = acc[i][j][r];
        if (seg == 0) {
          Cout[(size_t)m * 1024 + nn] = f2b(v);
        } else if (seg == 1) {
          (Cout + 8388608)[(size_t)m * 1024 + nn] = f2b(v);
        } else {
          int b = m >> 11, tq = m & 2047, hh = nn >> 6, d = nn & 63;
          (Cout + 16777216)[(((size_t)((b * 16 + hh) * 64 + d)) << 11) + tq] = f2b(v);
        }
      }
    }
  }
}

// ---------------- out-proj GEMM: 256x128 ring-3 (same structure as qkv), bias folded -----
// M=8192, N=1024, K=1024. Grid (32,8) = 256 blocks = exactly 1/CU, one full round, no tail.
// Replaces the 128x64-tile stage-drain version (R4): 2x intensity + pipelined staging.
__launch_bounds__(512, 2)
__global__ void gemm_proj(const unsigned short* __restrict__ A,
                          const unsigned short* __restrict__ Bw,
                          const float* __restrict__ bias,
                          float* __restrict__ out) {
  __shared__ unsigned short At[3][256 * 64];   // 3 x 32 KB
  __shared__ unsigned short Bt[3][128 * 64];   // 3 x 16 KB

  const int tid = threadIdx.x;
  const int lane = tid & 63;
  const int w = tid >> 6;
  const int quad = lane >> 4;
  const int l15 = lane & 15;
  const int m0 = blockIdx.x * 256;
  const int n0 = blockIdx.y * 128;
  const int wm = (w & 3) * 64;
  const int wn = (w >> 2) * 64;

  auto stageA = [&](int buf, int kt, int c) {
    int chunk = c * 512 + tid;
    int row = chunk >> 3;
    int scol = (chunk & 7) ^ (row & 7);
    load_lds16(A + (size_t)(m0 + row) * 1024 + kt + scol * 8,
               &At[buf][(c * 512 + (w << 6)) << 3]);
  };
  auto stageB = [&](int buf, int kt, int c) {
    int chunk = c * 512 + tid;
    int row = chunk >> 3;
    int scol = (chunk & 7) ^ (row & 7);
    load_lds16(Bw + (size_t)(n0 + row) * 1024 + kt + scol * 8,
               &Bt[buf][(c * 512 + (w << 6)) << 3]);
  };

  const f32x4 z4 = {0.f, 0.f, 0.f, 0.f};
  f32x4 acc[4][4];
#pragma unroll
  for (int i = 0; i < 4; ++i)
#pragma unroll
    for (int j = 0; j < 4; ++j) acc[i][j] = z4;

#pragma unroll
  for (int c = 0; c < 4; ++c) stageA(0, 0, c);
#pragma unroll
  for (int c = 0; c < 2; ++c) stageB(0, 0, c);
#pragma unroll
  for (int c = 0; c < 4; ++c) stageA(1, 64, c);
#pragma unroll
  for (int c = 0; c < 2; ++c) stageB(1, 64, c);
  asm volatile("s_waitcnt vmcnt(6)" ::: "memory");
  __builtin_amdgcn_s_barrier();
  __builtin_amdgcn_sched_barrier(0);

  int buf = 0;
  for (int t = 0; t < 16; ++t) {
    const int sbuf = (buf >= 1) ? buf - 1 : 2;
    const int skt = (t + 2) * 64;
    const bool st = (t < 14);

    {
      bf16x8 a0[4], b0[4];
#pragma unroll
      for (int i = 0; i < 4; ++i) {
        int rowA = wm + i * 16 + l15;
        a0[i] = *(const bf16x8*)&At[buf][rowA * 64 + ((quad ^ (rowA & 7)) << 3)];
      }
#pragma unroll
      for (int j = 0; j < 4; ++j) {
        int rowB = wn + j * 16 + l15;
        b0[j] = *(const bf16x8*)&Bt[buf][rowB * 64 + ((quad ^ (rowB & 7)) << 3)];
      }
      if (st) { stageA(sbuf, skt, 0); stageA(sbuf, skt, 1); stageA(sbuf, skt, 2); }
      __builtin_amdgcn_s_setprio(1);
#pragma unroll
      for (int i = 0; i < 4; ++i)
#pragma unroll
        for (int j = 0; j < 4; ++j)
          acc[i][j] = __builtin_amdgcn_mfma_f32_16x16x32_bf16(a0[i], b0[j], acc[i][j], 0, 0, 0);
      __builtin_amdgcn_s_setprio(0);
    }

    {
      bf16x8 a1[4], b1[4];
#pragma unroll
      for (int i = 0; i < 4; ++i) {
        int rowA = wm + i * 16 + l15;
        a1[i] = *(const bf16x8*)&At[buf][rowA * 64 + (((4 + quad) ^ (rowA & 7)) << 3)];
      }
#pragma unroll
      for (int j = 0; j < 4; ++j) {
        int rowB = wn + j * 16 + l15;
        b1[j] = *(const bf16x8*)&Bt[buf][rowB * 64 + (((4 + quad) ^ (rowB & 7)) << 3)];
      }
      if (st) { stageA(sbuf, skt, 3); stageB(sbuf, skt, 0); stageB(sbuf, skt, 1); }
      __builtin_amdgcn_s_setprio(1);
#pragma unroll
      for (int i = 0; i < 4; ++i)
#pragma unroll
        for (int j = 0; j < 4; ++j)
          acc[i][j] = __builtin_amdgcn_mfma_f32_16x16x32_bf16(a1[i], b1[j], acc[i][j], 0, 0, 0);
      __builtin_amdgcn_s_setprio(0);
      if (t < 14) {
        asm volatile("s_waitcnt vmcnt(6)" ::: "memory");
      } else if (t == 14) {
        asm volatile("s_waitcnt vmcnt(0)" ::: "memory");
      }
      __builtin_amdgcn_s_barrier();
      __builtin_amdgcn_sched_barrier(0);
    }

    buf = (buf < 2) ? buf + 1 : 0;
  }

  // epilogue: fp32 + bias. C/D layout: col = lane&15, row = quad*4 + reg.
#pragma unroll
  for (int i = 0; i < 4; ++i)
#pragma unroll
    for (int j = 0; j < 4; ++j) {
      int n = n0 + wn + j * 16 + l15;
      float bv = bias[n];
#pragma unroll
      for (int r = 0; r < 4; ++r) {
        int m = m0 + wm + i * 16 + quad * 4 + r;
        out[(size_t)m * 1024 + n] = acc[i][j][r] + bv;
      }
    }
}

// ---------------- causal flash attention (S^T form, fixed-max softmax, QBLK=128) ---------
// grid (bh=64, pp=8), 256 thr. Flat block id = bh + 64*pp -> XCD = bh%8: all 8 pp-blocks of
// a head land on ONE XCD; per-XCD K/V working set = 8 heads x 512 KB = 4 MB = L2.
// Block handles 128-row q-tiles {pp, 15-pp}: uniform 34 k-tile iters. Each wave owns 32 q
// rows (two 16-row groups): K/V frags read from LDS ONCE feed BOTH groups.
// Fixed max M0=11: p = 2^(raw*SC - 11); the 2^-11 factor cancels in O/l.
__launch_bounds__(256)
__global__ void attn_kernel(const unsigned short* __restrict__ Q,
                            const unsigned short* __restrict__ K,
                            const unsigned short* __restrict__ VT,
                            unsigned short* __restrict__ ctx) {
  __shared__ unsigned short Kt[2][64 * 64];   // 2 x 8 KB
  __shared__ unsigned short Vt[2][64 * 64];   // 2 x 8 KB
  __shared__ unsigned short Pt[128 * 64];     // 16 KB: P^T rows = block q rows (wave-local)

  const int tid = threadIdx.x;
  const int lane = tid & 63;
  const int w = tid >> 6;
  const int quad = lane >> 4;
  const int l15 = lane & 15;
  const int bh = blockIdx.x;            // head-major: keeps a head's K/V on one XCD
  const int pp = blockIdx.y;
  const int b = bh >> 4, h = bh & 15;

  const unsigned short* Kg = K + ((size_t)(b * 2048)) * 1024 + h * 64;  // +t*1024
  const unsigned short* Vg = VT + ((size_t)bh * 64) * 2048;             // +d*2048+t

  const float SC = 0.1803368801f;  // (1/sqrt(64)) * log2(e)
  const float M0 = 11.0f;          // fixed max in log2 domain

  for (int tt = 0; tt < 2; ++tt) {
    const int qt = tt ? (15 - pp) : pp;  // 128-row q-tile index
    const int qb = qt * 128;
    const int jn = 2 * qt + 2;           // # of 64-wide k-tiles

    // Q frags: 2 row-groups x 2 k-steps
    bf16x8 qa[2][2];
#pragma unroll
    for (int g = 0; g < 2; ++g) {
      const unsigned short* qbase =
          Q + ((size_t)(b * 2048 + qb + w * 32 + g * 16 + l15)) * 1024 + h * 64;
      qa[g][0] = *(const bf16x8*)(qbase + quad * 8);
      qa[g][1] = *(const bf16x8*)(qbase + 32 + quad * 8);
    }

    const f32x4 z4 = {0.f, 0.f, 0.f, 0.f};
    f32x4 o[2][4];
#pragma unroll
    for (int g = 0; g < 2; ++g)
#pragma unroll
      for (int nt = 0; nt < 4; ++nt) o[g][nt] = z4;
    float lrow[2] = {0.f, 0.f};

    if (tt) __syncthreads();  // protect LDS buffers from previous tile's readers

    // stage j=0 into buffer 0
#pragma unroll
    for (int c = 0; c < 2; ++c) {
      int chunk = c * 256 + tid;
      int row = chunk >> 3;
      int scol = (chunk & 7) ^ (row & 7);
      load_lds16(Kg + (size_t)row * 1024 + scol * 8, &Kt[0][((c * 256 + (w << 6)) << 3)]);
      load_lds16(Vg + ((size_t)row << 11) + scol * 8, &Vt[0][((c * 256 + (w << 6)) << 3)]);
    }

    int cur = 0;
    for (int j = 0; j < jn; ++j) {
      const int j0 = j * 64;
      __syncthreads();  // stage(j) drained; prior-iter LDS reads done

      if (j + 1 < jn) {  // prefetch j+1 into alternate buffer; overlaps compute below
        const int nj0 = j0 + 64;
#pragma unroll
        for (int c = 0; c < 2; ++c) {
          int chunk = c * 256 + tid;
          int row = chunk >> 3;
          int scol = (chunk & 7) ^ (row & 7);
          load_lds16(Kg + (size_t)(nj0 + row) * 1024 + scol * 8,
                     &Kt[cur ^ 1][((c * 256 + (w << 6)) << 3)]);
          load_lds16(Vg + ((size_t)row << 11) + nj0 + scol * 8,
                     &Vt[cur ^ 1][((c * 256 + (w << 6)) << 3)]);
        }
      }

      // S^T = K Q^T for both groups: kf read ONCE, 2 MFMA per read.
      f32x4 st[2][4];
#pragma unroll
      for (int g = 0; g < 2; ++g)
#pragma unroll
        for (int nt = 0; nt < 4; ++nt) st[g][nt] = z4;
#pragma unroll
      for (int ks = 0; ks < 2; ++ks) {
#pragma unroll
        for (int nt = 0; nt < 4; ++nt) {
          int rowK = nt * 16 + l15;
          bf16x8 kf = *(const bf16x8*)&Kt[cur][rowK * 64 + (((ks * 4 + quad) ^ (rowK & 7)) << 3)];
          st[0][nt] = __builtin_amdgcn_mfma_f32_16x16x32_bf16(kf, qa[0][ks], st[0][nt], 0, 0, 0);
          st[1][nt] = __builtin_amdgcn_mfma_f32_16x16x32_bf16(kf, qa[1][ks], st[1][nt], 0, 0, 0);
        }
      }

      // softmax: p = 2^(raw*SC - M0); causal mask; per-iter butterfly sum. Per group.
#pragma unroll
      for (int g = 0; g < 2; ++g) {
        const int qmin = qb + w * 32 + g * 16;
        const bool dg = (j0 + 63 > qmin);
        const int q = qmin + l15;
        float sum = 0.f;
#pragma unroll
        for (int nt = 0; nt < 4; ++nt) {
#pragma unroll
          for (int r = 0; r < 4; ++r) {
            float e = fmaf(st[g][nt][r], SC, -M0);
            if (dg) {
              int kpos = j0 + nt * 16 + quad * 4 + r;
              if (kpos > q) e = -1e30f;
            }
            float pv = __builtin_amdgcn_exp2f(e);
            st[g][nt][r] = pv;
            sum += pv;
          }
        }
        sum += __shfl_xor(sum, 16);
        sum += __shfl_xor(sum, 32);
        lrow[g] += sum;
      }

      // P^T -> Pt[qrow][kpos] (ushort4, swizzled by q&15), wave-local region (32 rows)
#pragma unroll
      for (int g = 0; g < 2; ++g) {
        const int qrow = w * 32 + g * 16 + l15;
#pragma unroll
        for (int nt = 0; nt < 4; ++nt) {
          ushort4 pk;
          pk.x = f2b(st[g][nt][0]); pk.y = f2b(st[g][nt][1]);
          pk.z = f2b(st[g][nt][2]); pk.w = f2b(st[g][nt][3]);
          int chunk = nt * 4 + quad;  // kpos chunk (4 shorts)
          *(ushort4*)&Pt[qrow * 64 + ((chunk ^ l15) << 2)] = pk;
        }
      }
      // no barrier: P region is wave-local

      // O += P V : vb read ONCE per (ks,nt), 2 MFMA per read.
#pragma unroll
      for (int ks = 0; ks < 2; ++ks) {
        int c0 = ks * 8 + quad * 2;
        union { ushort4 hh[2]; bf16x8 v; } pu[2];
#pragma unroll
        for (int g = 0; g < 2; ++g) {
          const int qrow = w * 32 + g * 16 + l15;
          pu[g].hh[0] = *(const ushort4*)&Pt[qrow * 64 + ((c0 ^ l15) << 2)];
          pu[g].hh[1] = *(const ushort4*)&Pt[qrow * 64 + (((c0 + 1) ^ l15) << 2)];
        }
#pragma unroll
        for (int nt = 0; nt < 4; ++nt) {
          int rowV = nt * 16 + l15;
          bf16x8 vb = *(const bf16x8*)&Vt[cur][rowV * 64 + (((ks * 4 + quad) ^ (rowV & 7)) << 3)];
          o[0][nt] = __builtin_amdgcn_mfma_f32_16x16x32_bf16(pu[0].v, vb, o[0][nt], 0, 0, 0);
          o[1][nt] = __builtin_amdgcn_mfma_f32_16x16x32_bf16(pu[1].v, vb, o[1][nt], 0, 0, 0);
        }
      }
      cur ^= 1;
    }

    // epilogue: ctx[b, q, h*64+d] bf16. O C-layout: row=q_local=quad*4+r, col=d=l15.
#pragma unroll
    for (int g = 0; g < 2; ++g) {
      float lf[4];
#pragma unroll
      for (int r = 0; r < 4; ++r) lf[r] = 1.f / __shfl(lrow[g], quad * 4 + r);
#pragma unroll
      for (int nt = 0; nt < 4; ++nt) {
#pragma unroll
        for (int r = 0; r < 4; ++r) {
          int q = qb + w * 32 + g * 16 + quad * 4 + r;
          int dcol = nt * 16 + l15;
          ctx[((size_t)(b * 2048 + q)) * 1024 + h * 64 + dcol] = f2b(o[g][nt][r] * lf[r]);
        }
      }
    }
  }
}

// ---------------- launcher ----------------
extern "C" void kernel_launch(void* const* d_in, const int* in_sizes, int n_in,
                              void* d_out, int out_size, void* d_ws, size_t ws_size,
                              hipStream_t stream) {
  const float* x  = (const float*)d_in[0];
  // d_in[1] = mask (causal, deterministic) — unused
  const float* Wq = (const float*)d_in[2];
  const float* Wk = (const float*)d_in[3];
  const float* Wv = (const float*)d_in[4];
  const float* Wo = (const float*)d_in[5];
  const float* bo = (const float*)d_in[6];
  float* out = (float*)d_out;

  unsigned short* xb  = (unsigned short*)d_ws;      // 8.4M elems (16 MB)
  unsigned short* wb  = xb + 8388608;               // 4 x 1M elems (8 MB) — Wq,Wk,Wv,Wo contiguous
  unsigned short* Qb  = wb + 4 * 1048576;           // Q; K at +8388608, VT at +16777216
  unsigned short* Kb  = Qb + 8388608;
  unsigned short* VTb = Kb + 8388608;
  unsigned short* ctxb = xb;                        // overlay: x dead after QKV

  cast_kernel<<<6144, 256, 0, stream>>>(x, Wq, Wk, Wv, Wo, xb, wb);

  // fused QKV: N=3072 (Wq|Wk|Wv contiguous in wb), 256x128 tiles, ring-3, 1 barrier/tile
  gemm_qkv<<<dim3(32, 24), 512, 0, stream>>>(xb, wb, Qb);

  // attn: grid (bh, pp) — head-major for XCD/L2 locality; 128-row q-tile pairs {pp, 15-pp}
  attn_kernel<<<dim3(64, 8), 256, 0, stream>>>(Qb, Kb, VTb, ctxb);

  // out proj: 256x128 ring-3, grid (32,8)=256 blocks (1/CU, no tail), bias folded
  gemm_proj<<<dim3(32, 8), 512, 0, stream>>>(ctxb, wb + 3 * 1048576, bo, out);
}

// Round 8
// 270.821 us; speedup vs baseline: 1.1495x; 1.0359x over previous
//
#include <hip/hip_runtime.h>
#include <hip/hip_bf16.h>

// MultiHeadAttention: B=4, T=2048, D=1024, H=16, dk=64, causal.
// cast->bf16 | fused QKV gemm (256x128 ring-3, 1 barrier/tile) | flash attn (QBLK=128, LPT) | out proj (ring-3).

typedef __attribute__((ext_vector_type(8))) short bf16x8;   // 8 bf16 = 4 VGPRs (A/B frag)
typedef __attribute__((ext_vector_type(4))) float f32x4;    // C/D frag

__device__ __forceinline__ unsigned short f2b(float x) {
  __hip_bfloat16 h = __float2bfloat16(x);
  return __builtin_bit_cast(unsigned short, h);
}

// async global->LDS, 16B per lane. LDS dst = wave-uniform base + lane*16.
__device__ __forceinline__ void load_lds16(const void* g, void* l) {
  __builtin_amdgcn_global_load_lds((__attribute__((address_space(1))) void*)g,
                                   (__attribute__((address_space(3))) void*)l,
                                   16, 0, 0);
}

// ---------------- fused cast kernel: x (1048576 chunks) then Wq|Wk|Wv|Wo (131072 each) ----
__global__ void cast_kernel(const float* __restrict__ x,
                            const float* __restrict__ w0, const float* __restrict__ w1,
                            const float* __restrict__ w2, const float* __restrict__ w3,
                            unsigned short* __restrict__ xb, unsigned short* __restrict__ wb) {
  int i = blockIdx.x * 256 + threadIdx.x;
  const float* src;
  unsigned short* dst;
  int c;
  if (i < 1048576) {
    src = x; dst = xb; c = i;
  } else {
    int cw = i - 1048576;
    int wi = cw >> 17;           // which weight
    c = cw & 131071;
    src = (wi == 0) ? w0 : (wi == 1) ? w1 : (wi == 2) ? w2 : w3;
    dst = wb + ((size_t)wi << 20);
  }
  const float4* s4 = (const float4*)src;
  float4 a = s4[2 * c], b = s4[2 * c + 1];
  union { unsigned short u[8]; uint4 v; } r;
  r.u[0] = f2b(a.x); r.u[1] = f2b(a.y); r.u[2] = f2b(a.z); r.u[3] = f2b(a.w);
  r.u[4] = f2b(b.x); r.u[5] = f2b(b.y); r.u[6] = f2b(b.z); r.u[7] = f2b(b.w);
  ((uint4*)dst)[c] = r.v;
}

// ---------------- fused QKV GEMM: 256x128 tile, BK=64, ring-of-3 LDS, 1 barrier/tile -----
// M=8192, N=3072, K=1024. 512 thr = 8 waves of 64x64. Grid 32x24 = 768 = 3*256 (no tail).
// Ring-3 invariant: staging targets buf+2 (never live) -> ONE barrier per K-tile; waves
// drift within a tile so LDS-read bursts overlap other waves' MFMAs. vmcnt(6) counted.
__launch_bounds__(512, 2)
__global__ void gemm_qkv(const unsigned short* __restrict__ A,
                         const unsigned short* __restrict__ Bw,
                         unsigned short* __restrict__ Cout) {
  __shared__ unsigned short At[3][256 * 64];   // 3 x 32 KB
  __shared__ unsigned short Bt[3][128 * 64];   // 3 x 16 KB  (total 144 KB)

  const int tid = threadIdx.x;
  const int lane = tid & 63;
  const int w = tid >> 6;          // 0..7
  const int quad = lane >> 4;
  const int l15 = lane & 15;
  const int m0 = blockIdx.x * 256;
  const int n0 = blockIdx.y * 128;
  const int wm = (w & 3) * 64;     // wave m-offset (4 m-waves)
  const int wn = (w >> 2) * 64;    // wave n-offset (2 n-waves)

  auto stageA = [&](int buf, int kt, int c) {
    int chunk = c * 512 + tid;
    int row = chunk >> 3;
    int scol = (chunk & 7) ^ (row & 7);
    load_lds16(A + (size_t)(m0 + row) * 1024 + kt + scol * 8,
               &At[buf][(c * 512 + (w << 6)) << 3]);
  };
  auto stageB = [&](int buf, int kt, int c) {
    int chunk = c * 512 + tid;
    int row = chunk >> 3;
    int scol = (chunk & 7) ^ (row & 7);
    load_lds16(Bw + (size_t)(n0 + row) * 1024 + kt + scol * 8,
               &Bt[buf][(c * 512 + (w << 6)) << 3]);
  };

  const f32x4 z4 = {0.f, 0.f, 0.f, 0.f};
  f32x4 acc[4][4];
#pragma unroll
  for (int i = 0; i < 4; ++i)
#pragma unroll
    for (int j = 0; j < 4; ++j) acc[i][j] = z4;

  // prologue: stage tiles 0 and 1; wait t0 complete (t1 in flight).
#pragma unroll
  for (int c = 0; c < 4; ++c) stageA(0, 0, c);
#pragma unroll
  for (int c = 0; c < 2; ++c) stageB(0, 0, c);
#pragma unroll
  for (int c = 0; c < 4; ++c) stageA(1, 64, c);
#pragma unroll
  for (int c = 0; c < 2; ++c) stageB(1, 64, c);
  asm volatile("s_waitcnt vmcnt(6)" ::: "memory");
  __builtin_amdgcn_s_barrier();
  __builtin_amdgcn_sched_barrier(0);

  int buf = 0;
  for (int t = 0; t < 16; ++t) {
    const int sbuf = (buf >= 1) ? buf - 1 : 2;   // (t+2)%3
    const int skt = (t + 2) * 64;
    const bool st = (t < 14);

    // ---- k-slice 0: 8 reads (4A+4B) | 3 stage | 16 MFMA (no barrier) ----
    {
      bf16x8 a0[4], b0[4];
#pragma unroll
      for (int i = 0; i < 4; ++i) {
        int rowA = wm + i * 16 + l15;
        a0[i] = *(const bf16x8*)&At[buf][rowA * 64 + ((quad ^ (rowA & 7)) << 3)];
      }
#pragma unroll
      for (int j = 0; j < 4; ++j) {
        int rowB = wn + j * 16 + l15;
        b0[j] = *(const bf16x8*)&Bt[buf][rowB * 64 + ((quad ^ (rowB & 7)) << 3)];
      }
      if (st) { stageA(sbuf, skt, 0); stageA(sbuf, skt, 1); stageA(sbuf, skt, 2); }
      __builtin_amdgcn_s_setprio(1);
#pragma unroll
      for (int i = 0; i < 4; ++i)
#pragma unroll
        for (int j = 0; j < 4; ++j)
          acc[i][j] = __builtin_amdgcn_mfma_f32_16x16x32_bf16(a0[i], b0[j], acc[i][j], 0, 0, 0);
      __builtin_amdgcn_s_setprio(0);
    }

    // ---- k-slice 1: 8 reads | 3 stage | 16 MFMA | counted vmcnt | ONE barrier ----
    {
      bf16x8 a1[4], b1[4];
#pragma unroll
      for (int i = 0; i < 4; ++i) {
        int rowA = wm + i * 16 + l15;
        a1[i] = *(const bf16x8*)&At[buf][rowA * 64 + (((4 + quad) ^ (rowA & 7)) << 3)];
      }
#pragma unroll
      for (int j = 0; j < 4; ++j) {
        int rowB = wn + j * 16 + l15;
        b1[j] = *(const bf16x8*)&Bt[buf][rowB * 64 + (((4 + quad) ^ (rowB & 7)) << 3)];
      }
      if (st) { stageA(sbuf, skt, 3); stageB(sbuf, skt, 0); stageB(sbuf, skt, 1); }
      __builtin_amdgcn_s_setprio(1);
#pragma unroll
      for (int i = 0; i < 4; ++i)
#pragma unroll
        for (int j = 0; j < 4; ++j)
          acc[i][j] = __builtin_amdgcn_mfma_f32_16x16x32_bf16(a1[i], b1[j], acc[i][j], 0, 0, 0);
      __builtin_amdgcn_s_setprio(0);
      if (t < 14) {
        asm volatile("s_waitcnt vmcnt(6)" ::: "memory");
      } else if (t == 14) {
        asm volatile("s_waitcnt vmcnt(0)" ::: "memory");
      }
      __builtin_amdgcn_s_barrier();
      __builtin_amdgcn_sched_barrier(0);
    }

    buf = (buf < 2) ? buf + 1 : 0;
  }

  // epilogue. C/D layout: col = lane&15, row = quad*4 + reg.
  const int seg = n0 >> 10;  // uniform per block
#pragma unroll
  for (int i = 0; i < 4; ++i) {
#pragma unroll
    for (int j = 0; j < 4; ++j) {
#pragma unroll
      for (int r = 0; r < 4; ++r) {
        int m = m0 + wm + i * 16 + quad * 4 + r;
        int n = n0 + wn + j * 16 + l15;
        int nn = n & 1023;
        float v = acc[i][j][r];
        if (seg == 0) {
          Cout[(size_t)m * 1024 + nn] = f2b(v);
        } else if (seg == 1) {
          (Cout + 8388608)[(size_t)m * 1024 + nn] = f2b(v);
        } else {
          int b = m >> 11, tq = m & 2047, hh = nn >> 6, d = nn & 63;
          (Cout + 16777216)[(((size_t)((b * 16 + hh) * 64 + d)) << 11) + tq] = f2b(v);
        }
      }
    }
  }
}

// ---------------- out-proj GEMM: 256x128 ring-3 (same structure as qkv), bias folded -----
// M=8192, N=1024, K=1024. Grid (32,8) = 256 blocks = exactly 1/CU, one full round, no tail.
__launch_bounds__(512, 2)
__global__ void gemm_proj(const unsigned short* __restrict__ A,
                          const unsigned short* __restrict__ Bw,
                          const float* __restrict__ bias,
                          float* __restrict__ out) {
  __shared__ unsigned short At[3][256 * 64];   // 3 x 32 KB
  __shared__ unsigned short Bt[3][128 * 64];   // 3 x 16 KB

  const int tid = threadIdx.x;
  const int lane = tid & 63;
  const int w = tid >> 6;
  const int quad = lane >> 4;
  const int l15 = lane & 15;
  const int m0 = blockIdx.x * 256;
  const int n0 = blockIdx.y * 128;
  const int wm = (w & 3) * 64;
  const int wn = (w >> 2) * 64;

  auto stageA = [&](int buf, int kt, int c) {
    int chunk = c * 512 + tid;
    int row = chunk >> 3;
    int scol = (chunk & 7) ^ (row & 7);
    load_lds16(A + (size_t)(m0 + row) * 1024 + kt + scol * 8,
               &At[buf][(c * 512 + (w << 6)) << 3]);
  };
  auto stageB = [&](int buf, int kt, int c) {
    int chunk = c * 512 + tid;
    int row = chunk >> 3;
    int scol = (chunk & 7) ^ (row & 7);
    load_lds16(Bw + (size_t)(n0 + row) * 1024 + kt + scol * 8,
               &Bt[buf][(c * 512 + (w << 6)) << 3]);
  };

  const f32x4 z4 = {0.f, 0.f, 0.f, 0.f};
  f32x4 acc[4][4];
#pragma unroll
  for (int i = 0; i < 4; ++i)
#pragma unroll
    for (int j = 0; j < 4; ++j) acc[i][j] = z4;

#pragma unroll
  for (int c = 0; c < 4; ++c) stageA(0, 0, c);
#pragma unroll
  for (int c = 0; c < 2; ++c) stageB(0, 0, c);
#pragma unroll
  for (int c = 0; c < 4; ++c) stageA(1, 64, c);
#pragma unroll
  for (int c = 0; c < 2; ++c) stageB(1, 64, c);
  asm volatile("s_waitcnt vmcnt(6)" ::: "memory");
  __builtin_amdgcn_s_barrier();
  __builtin_amdgcn_sched_barrier(0);

  int buf = 0;
  for (int t = 0; t < 16; ++t) {
    const int sbuf = (buf >= 1) ? buf - 1 : 2;
    const int skt = (t + 2) * 64;
    const bool st = (t < 14);

    {
      bf16x8 a0[4], b0[4];
#pragma unroll
      for (int i = 0; i < 4; ++i) {
        int rowA = wm + i * 16 + l15;
        a0[i] = *(const bf16x8*)&At[buf][rowA * 64 + ((quad ^ (rowA & 7)) << 3)];
      }
#pragma unroll
      for (int j = 0; j < 4; ++j) {
        int rowB = wn + j * 16 + l15;
        b0[j] = *(const bf16x8*)&Bt[buf][rowB * 64 + ((quad ^ (rowB & 7)) << 3)];
      }
      if (st) { stageA(sbuf, skt, 0); stageA(sbuf, skt, 1); stageA(sbuf, skt, 2); }
      __builtin_amdgcn_s_setprio(1);
#pragma unroll
      for (int i = 0; i < 4; ++i)
#pragma unroll
        for (int j = 0; j < 4; ++j)
          acc[i][j] = __builtin_amdgcn_mfma_f32_16x16x32_bf16(a0[i], b0[j], acc[i][j], 0, 0, 0);
      __builtin_amdgcn_s_setprio(0);
    }

    {
      bf16x8 a1[4], b1[4];
#pragma unroll
      for (int i = 0; i < 4; ++i) {
        int rowA = wm + i * 16 + l15;
        a1[i] = *(const bf16x8*)&At[buf][rowA * 64 + (((4 + quad) ^ (rowA & 7)) << 3)];
      }
#pragma unroll
      for (int j = 0; j < 4; ++j) {
        int rowB = wn + j * 16 + l15;
        b1[j] = *(const bf16x8*)&Bt[buf][rowB * 64 + (((4 + quad) ^ (rowB & 7)) << 3)];
      }
      if (st) { stageA(sbuf, skt, 3); stageB(sbuf, skt, 0); stageB(sbuf, skt, 1); }
      __builtin_amdgcn_s_setprio(1);
#pragma unroll
      for (int i = 0; i < 4; ++i)
#pragma unroll
        for (int j = 0; j < 4; ++j)
          acc[i][j] = __builtin_amdgcn_mfma_f32_16x16x32_bf16(a1[i], b1[j], acc[i][j], 0, 0, 0);
      __builtin_amdgcn_s_setprio(0);
      if (t < 14) {
        asm volatile("s_waitcnt vmcnt(6)" ::: "memory");
      } else if (t == 14) {
        asm volatile("s_waitcnt vmcnt(0)" ::: "memory");
      }
      __builtin_amdgcn_s_barrier();
      __builtin_amdgcn_sched_barrier(0);
    }

    buf = (buf < 2) ? buf + 1 : 0;
  }

  // epilogue: fp32 + bias. C/D layout: col = lane&15, row = quad*4 + reg.
#pragma unroll
  for (int i = 0; i < 4; ++i)
#pragma unroll
    for (int j = 0; j < 4; ++j) {
      int n = n0 + wn + j * 16 + l15;
      float bv = bias[n];
#pragma unroll
      for (int r = 0; r < 4; ++r) {
        int m = m0 + wm + i * 16 + quad * 4 + r;
        out[(size_t)m * 1024 + n] = acc[i][j][r] + bv;
      }
    }
}

// ---------------- causal flash attention (S^T form, fixed-max softmax, QBLK=128) ---------
// R6 post-mortem: paired grid (64,8)=512 blocks capped residency at 2 blocks/CU = 2 waves/
// SIMD -> the serial QK^T->softmax->pack->PV chain can't overlap across waves (MfmaUtil
// 18.7%, Occ 19.4%, nothing saturated). LDS (48KB) allows 3 blocks/CU; VGPR (104) allows 4
// waves/SIMD. R7/R8: UN-PAIR q-tiles -> grid (bh=64, 16) = 1024 blocks, one 128-row q-tile
// each (work ~ qt+1, non-uniform); LPT order (qt = 15 - blockIdx.y: longest blocks dispatch
// first, short ones backfill). XCD locality unchanged: flat%8 = bh%8 -> head's K/V on one
// XCD L2. K-loop body byte-identical to R6. (R7 bench was an infra failure, not a verdict.)
__launch_bounds__(256, 3)
__global__ void attn_kernel(const unsigned short* __restrict__ Q,
                            const unsigned short* __restrict__ K,
                            const unsigned short* __restrict__ VT,
                            unsigned short* __restrict__ ctx) {
  __shared__ unsigned short Kt[2][64 * 64];   // 2 x 8 KB
  __shared__ unsigned short Vt[2][64 * 64];   // 2 x 8 KB
  __shared__ unsigned short Pt[128 * 64];     // 16 KB: P^T rows = block q rows (wave-local)

  const int tid = threadIdx.x;
  const int lane = tid & 63;
  const int w = tid >> 6;
  const int quad = lane >> 4;
  const int l15 = lane & 15;
  const int bh = blockIdx.x;            // head-major: keeps a head's K/V on one XCD
  const int qt = 15 - blockIdx.y;       // LPT: longest q-tiles dispatched first
  const int b = bh >> 4, h = bh & 15;

  const unsigned short* Kg = K + ((size_t)(b * 2048)) * 1024 + h * 64;  // +t*1024
  const unsigned short* Vg = VT + ((size_t)bh * 64) * 2048;             // +d*2048+t

  const float SC = 0.1803368801f;  // (1/sqrt(64)) * log2(e)
  const float M0 = 11.0f;          // fixed max in log2 domain

  const int qb = qt * 128;
  const int jn = 2 * qt + 2;           // # of 64-wide k-tiles

  // Q frags: 2 row-groups x 2 k-steps
  bf16x8 qa[2][2];
#pragma unroll
  for (int g = 0; g < 2; ++g) {
    const unsigned short* qbase =
        Q + ((size_t)(b * 2048 + qb + w * 32 + g * 16 + l15)) * 1024 + h * 64;
    qa[g][0] = *(const bf16x8*)(qbase + quad * 8);
    qa[g][1] = *(const bf16x8*)(qbase + 32 + quad * 8);
  }

  const f32x4 z4 = {0.f, 0.f, 0.f, 0.f};
  f32x4 o[2][4];
#pragma unroll
  for (int g = 0; g < 2; ++g)
#pragma unroll
    for (int nt = 0; nt < 4; ++nt) o[g][nt] = z4;
  float lrow[2] = {0.f, 0.f};

  // stage j=0 into buffer 0
#pragma unroll
  for (int c = 0; c < 2; ++c) {
    int chunk = c * 256 + tid;
    int row = chunk >> 3;
    int scol = (chunk & 7) ^ (row & 7);
    load_lds16(Kg + (size_t)row * 1024 + scol * 8, &Kt[0][((c * 256 + (w << 6)) << 3)]);
    load_lds16(Vg + ((size_t)row << 11) + scol * 8, &Vt[0][((c * 256 + (w << 6)) << 3)]);
  }

  int cur = 0;
  for (int j = 0; j < jn; ++j) {
    const int j0 = j * 64;
    __syncthreads();  // stage(j) drained; prior-iter LDS reads done

    if (j + 1 < jn) {  // prefetch j+1 into alternate buffer; overlaps compute below
      const int nj0 = j0 + 64;
#pragma unroll
      for (int c = 0; c < 2; ++c) {
        int chunk = c * 256 + tid;
        int row = chunk >> 3;
        int scol = (chunk & 7) ^ (row & 7);
        load_lds16(Kg + (size_t)(nj0 + row) * 1024 + scol * 8,
                   &Kt[cur ^ 1][((c * 256 + (w << 6)) << 3)]);
        load_lds16(Vg + ((size_t)row << 11) + nj0 + scol * 8,
                   &Vt[cur ^ 1][((c * 256 + (w << 6)) << 3)]);
      }
    }

    // S^T = K Q^T for both groups: kf read ONCE, 2 MFMA per read.
    f32x4 st[2][4];
#pragma unroll
    for (int g = 0; g < 2; ++g)
#pragma unroll
      for (int nt = 0; nt < 4; ++nt) st[g][nt] = z4;
#pragma unroll
    for (int ks = 0; ks < 2; ++ks) {
#pragma unroll
      for (int nt = 0; nt < 4; ++nt) {
        int rowK = nt * 16 + l15;
        bf16x8 kf = *(const bf16x8*)&Kt[cur][rowK * 64 + (((ks * 4 + quad) ^ (rowK & 7)) << 3)];
        st[0][nt] = __builtin_amdgcn_mfma_f32_16x16x32_bf16(kf, qa[0][ks], st[0][nt], 0, 0, 0);
        st[1][nt] = __builtin_amdgcn_mfma_f32_16x16x32_bf16(kf, qa[1][ks], st[1][nt], 0, 0, 0);
      }
    }

    // softmax: p = 2^(raw*SC - M0); causal mask; per-iter butterfly sum. Per group.
#pragma unroll
    for (int g = 0; g < 2; ++g) {
      const int qmin = qb + w * 32 + g * 16;
      const bool dg = (j0 + 63 > qmin);
      const int q = qmin + l15;
      float sum = 0.f;
#pragma unroll
      for (int nt = 0; nt < 4; ++nt) {
#pragma unroll
        for (int r = 0; r < 4; ++r) {
          float e = fmaf(st[g][nt][r], SC, -M0);
          if (dg) {
            int kpos = j0 + nt * 16 + quad * 4 + r;
            if (kpos > q) e = -1e30f;
          }
          float pv = __builtin_amdgcn_exp2f(e);
          st[g][nt][r] = pv;
          sum += pv;
        }
      }
      sum += __shfl_xor(sum, 16);
      sum += __shfl_xor(sum, 32);
      lrow[g] += sum;
    }

    // P^T -> Pt[qrow][kpos] (ushort4, swizzled by q&15), wave-local region (32 rows)
#pragma unroll
    for (int g = 0; g < 2; ++g) {
      const int qrow = w * 32 + g * 16 + l15;
#pragma unroll
      for (int nt = 0; nt < 4; ++nt) {
        ushort4 pk;
        pk.x = f2b(st[g][nt][0]); pk.y = f2b(st[g][nt][1]);
        pk.z = f2b(st[g][nt][2]); pk.w = f2b(st[g][nt][3]);
        int chunk = nt * 4 + quad;  // kpos chunk (4 shorts)
        *(ushort4*)&Pt[qrow * 64 + ((chunk ^ l15) << 2)] = pk;
      }
    }
    // no barrier: P region is wave-local

    // O += P V : vb read ONCE per (ks,nt), 2 MFMA per read.
#pragma unroll
    for (int ks = 0; ks < 2; ++ks) {
      int c0 = ks * 8 + quad * 2;
      union { ushort4 hh[2]; bf16x8 v; } pu[2];
#pragma unroll
      for (int g = 0; g < 2; ++g) {
        const int qrow = w * 32 + g * 16 + l15;
        pu[g].hh[0] = *(const ushort4*)&Pt[qrow * 64 + ((c0 ^ l15) << 2)];
        pu[g].hh[1] = *(const ushort4*)&Pt[qrow * 64 + (((c0 + 1) ^ l15) << 2)];
      }
#pragma unroll
      for (int nt = 0; nt < 4; ++nt) {
        int rowV = nt * 16 + l15;
        bf16x8 vb = *(const bf16x8*)&Vt[cur][rowV * 64 + (((ks * 4 + quad) ^ (rowV & 7)) << 3)];
        o[0][nt] = __builtin_amdgcn_mfma_f32_16x16x32_bf16(pu[0].v, vb, o[0][nt], 0, 0, 0);
        o[1][nt] = __builtin_amdgcn_mfma_f32_16x16x32_bf16(pu[1].v, vb, o[1][nt], 0, 0, 0);
      }
    }
    cur ^= 1;
  }

  // epilogue: ctx[b, q, h*64+d] bf16. O C-layout: row=q_local=quad*4+r, col=d=l15.
#pragma unroll
  for (int g = 0; g < 2; ++g) {
    float lf[4];
#pragma unroll
    for (int r = 0; r < 4; ++r) lf[r] = 1.f / __shfl(lrow[g], quad * 4 + r);
#pragma unroll
    for (int nt = 0; nt < 4; ++nt) {
#pragma unroll
      for (int r = 0; r < 4; ++r) {
        int q = qb + w * 32 + g * 16 + quad * 4 + r;
        int dcol = nt * 16 + l15;
        ctx[((size_t)(b * 2048 + q)) * 1024 + h * 64 + dcol] = f2b(o[g][nt][r] * lf[r]);
      }
    }
  }
}

// ---------------- launcher ----------------
extern "C" void kernel_launch(void* const* d_in, const int* in_sizes, int n_in,
                              void* d_out, int out_size, void* d_ws, size_t ws_size,
                              hipStream_t stream) {
  const float* x  = (const float*)d_in[0];
  // d_in[1] = mask (causal, deterministic) — unused
  const float* Wq = (const float*)d_in[2];
  const float* Wk = (const float*)d_in[3];
  const float* Wv = (const float*)d_in[4];
  const float* Wo = (const float*)d_in[5];
  const float* bo = (const float*)d_in[6];
  float* out = (float*)d_out;

  unsigned short* xb  = (unsigned short*)d_ws;      // 8.4M elems (16 MB)
  unsigned short* wb  = xb + 8388608;               // 4 x 1M elems (8 MB) — Wq,Wk,Wv,Wo contiguous
  unsigned short* Qb  = wb + 4 * 1048576;           // Q; K at +8388608, VT at +16777216
  unsigned short* Kb  = Qb + 8388608;
  unsigned short* VTb = Kb + 8388608;
  unsigned short* ctxb = xb;                        // overlay: x dead after QKV

  cast_kernel<<<6144, 256, 0, stream>>>(x, Wq, Wk, Wv, Wo, xb, wb);

  // fused QKV: N=3072 (Wq|Wk|Wv contiguous in wb), 256x128 tiles, ring-3, 1 barrier/tile
  gemm_qkv<<<dim3(32, 24), 512, 0, stream>>>(xb, wb, Qb);

  // attn: grid (bh, 16) — one 128-row q-tile per block, LPT order, 1024 blocks (3/CU resident)
  attn_kernel<<<dim3(64, 16), 256, 0, stream>>>(Qb, Kb, VTb, ctxb);

  // out proj: 256x128 ring-3, grid (32,8)=256 blocks (1/CU, no tail), bias folded
  gemm_proj<<<dim3(32, 8), 512, 0, stream>>>(ctxb, wb + 3 * 1048576, bo, out);
}

// Round 9
// 252.704 us; speedup vs baseline: 1.2319x; 1.0717x over previous
//
#include <hip/hip_runtime.h>
#include <hip/hip_bf16.h>

// MultiHeadAttention: B=4, T=2048, D=1024, H=16, dk=64, causal.
// cast->bf16 | fused QKV gemm (256x128 ring-3, hoisted reads + SIMD-parity stagger) |
// flash attn (QBLK=128, LPT) | out proj (ring-3, same schedule).

typedef __attribute__((ext_vector_type(8))) short bf16x8;   // 8 bf16 = 4 VGPRs (A/B frag)
typedef __attribute__((ext_vector_type(4))) float f32x4;    // C/D frag

__device__ __forceinline__ unsigned short f2b(float x) {
  __hip_bfloat16 h = __float2bfloat16(x);
  return __builtin_bit_cast(unsigned short, h);
}

// async global->LDS, 16B per lane. LDS dst = wave-uniform base + lane*16.
__device__ __forceinline__ void load_lds16(const void* g, void* l) {
  __builtin_amdgcn_global_load_lds((__attribute__((address_space(1))) void*)g,
                                   (__attribute__((address_space(3))) void*)l,
                                   16, 0, 0);
}

// ---------------- fused cast kernel: x (1048576 chunks) then Wq|Wk|Wv|Wo (131072 each) ----
__global__ void cast_kernel(const float* __restrict__ x,
                            const float* __restrict__ w0, const float* __restrict__ w1,
                            const float* __restrict__ w2, const float* __restrict__ w3,
                            unsigned short* __restrict__ xb, unsigned short* __restrict__ wb) {
  int i = blockIdx.x * 256 + threadIdx.x;
  const float* src;
  unsigned short* dst;
  int c;
  if (i < 1048576) {
    src = x; dst = xb; c = i;
  } else {
    int cw = i - 1048576;
    int wi = cw >> 17;           // which weight
    c = cw & 131071;
    src = (wi == 0) ? w0 : (wi == 1) ? w1 : (wi == 2) ? w2 : w3;
    dst = wb + ((size_t)wi << 20);
  }
  const float4* s4 = (const float4*)src;
  float4 a = s4[2 * c], b = s4[2 * c + 1];
  union { unsigned short u[8]; uint4 v; } r;
  r.u[0] = f2b(a.x); r.u[1] = f2b(a.y); r.u[2] = f2b(a.z); r.u[3] = f2b(a.w);
  r.u[4] = f2b(b.x); r.u[5] = f2b(b.y); r.u[6] = f2b(b.z); r.u[7] = f2b(b.w);
  ((uint4*)dst)[c] = r.v;
}

// ---------------- fused QKV GEMM: 256x128 tile, BK=64, ring-of-3 LDS, 1 barrier/tile -----
// M=8192, N=3072, K=1024. 512 thr = 8 waves of 64x64. Grid 32x24 = 768 = 3*256 (no tail).
// LDS 144KB -> 1 block/CU = 2 waves/SIMD. R8 post-mortem: K-tile slot ~7800 cyc vs LDS
// floor ~1920 + MFMA 1241 -> 2x above floor. Cause: barrier releases all 8 waves at once,
// all burst 8 ds_reads -> 64-deep LDS queue (~770cyc) with MFMA idle, alternating bursts.
// R9 fix: (1) hoist BOTH k-slices' reads upfront (16 reads, stages interleaved) then the
// full 32-MFMA cluster -- compiler's fine lgkmcnt starts slice-1 MFMAs while slice-2 reads
// drain; (2) SIMD-parity slice order (waves w and w+4 share a SIMD -> opposite order) so
// the two waves on a SIMD wait on opposite ends of the read queue. Ring-3 invariant + one
// barrier/tile + counted vmcnt(6) unchanged (R6-verified).
__launch_bounds__(512, 2)
__global__ void gemm_qkv(const unsigned short* __restrict__ A,
                         const unsigned short* __restrict__ Bw,
                         unsigned short* __restrict__ Cout) {
  __shared__ unsigned short At[3][256 * 64];   // 3 x 32 KB
  __shared__ unsigned short Bt[3][128 * 64];   // 3 x 16 KB  (total 144 KB)

  const int tid = threadIdx.x;
  const int lane = tid & 63;
  const int w = tid >> 6;          // 0..7
  const int quad = lane >> 4;
  const int l15 = lane & 15;
  const int m0 = blockIdx.x * 256;
  const int n0 = blockIdx.y * 128;
  const int wm = (w & 3) * 64;     // wave m-offset (4 m-waves)
  const int wn = (w >> 2) * 64;    // wave n-offset (2 n-waves)
  const int sf = ((w >> 2) & 1) << 2;  // first k-slice quad-offset (0|4), per SIMD parity
  const int ss = 4 - sf;               // second k-slice

  auto stageA = [&](int buf, int kt, int c) {
    int chunk = c * 512 + tid;
    int row = chunk >> 3;
    int scol = (chunk & 7) ^ (row & 7);
    load_lds16(A + (size_t)(m0 + row) * 1024 + kt + scol * 8,
               &At[buf][(c * 512 + (w << 6)) << 3]);
  };
  auto stageB = [&](int buf, int kt, int c) {
    int chunk = c * 512 + tid;
    int row = chunk >> 3;
    int scol = (chunk & 7) ^ (row & 7);
    load_lds16(Bw + (size_t)(n0 + row) * 1024 + kt + scol * 8,
               &Bt[buf][(c * 512 + (w << 6)) << 3]);
  };

  const f32x4 z4 = {0.f, 0.f, 0.f, 0.f};
  f32x4 acc[4][4];
#pragma unroll
  for (int i = 0; i < 4; ++i)
#pragma unroll
    for (int j = 0; j < 4; ++j) acc[i][j] = z4;

  // prologue: stage tiles 0 and 1; wait t0 complete (t1 in flight).
#pragma unroll
  for (int c = 0; c < 4; ++c) stageA(0, 0, c);
#pragma unroll
  for (int c = 0; c < 2; ++c) stageB(0, 0, c);
#pragma unroll
  for (int c = 0; c < 4; ++c) stageA(1, 64, c);
#pragma unroll
  for (int c = 0; c < 2; ++c) stageB(1, 64, c);
  asm volatile("s_waitcnt vmcnt(6)" ::: "memory");
  __builtin_amdgcn_s_barrier();
  __builtin_amdgcn_sched_barrier(0);

  int buf = 0;
  for (int t = 0; t < 16; ++t) {
    const int sbuf = (buf >= 1) ? buf - 1 : 2;   // (t+2)%3
    const int skt = (t + 2) * 64;
    const bool st = (t < 14);

    bf16x8 aF[4], bF[4], aS[4], bS[4];

    // ---- hoisted reads: first slice (parity-dependent), stages interleaved ----
#pragma unroll
    for (int i = 0; i < 4; ++i) {
      int rowA = wm + i * 16 + l15;
      aF[i] = *(const bf16x8*)&At[buf][rowA * 64 + (((sf + quad) ^ (rowA & 7)) << 3)];
    }
#pragma unroll
    for (int j = 0; j < 4; ++j) {
      int rowB = wn + j * 16 + l15;
      bF[j] = *(const bf16x8*)&Bt[buf][rowB * 64 + (((sf + quad) ^ (rowB & 7)) << 3)];
    }
    if (st) { stageA(sbuf, skt, 0); stageA(sbuf, skt, 1); stageA(sbuf, skt, 2); }
    // ---- second slice reads ----
#pragma unroll
    for (int i = 0; i < 4; ++i) {
      int rowA = wm + i * 16 + l15;
      aS[i] = *(const bf16x8*)&At[buf][rowA * 64 + (((ss + quad) ^ (rowA & 7)) << 3)];
    }
#pragma unroll
    for (int j = 0; j < 4; ++j) {
      int rowB = wn + j * 16 + l15;
      bS[j] = *(const bf16x8*)&Bt[buf][rowB * 64 + (((ss + quad) ^ (rowB & 7)) << 3)];
    }
    if (st) { stageA(sbuf, skt, 3); stageB(sbuf, skt, 0); stageB(sbuf, skt, 1); }

    // ---- 32-MFMA cluster: first-slice MFMAs start as soon as their frags land ----
    __builtin_amdgcn_s_setprio(1);
#pragma unroll
    for (int i = 0; i < 4; ++i)
#pragma unroll
      for (int j = 0; j < 4; ++j)
        acc[i][j] = __builtin_amdgcn_mfma_f32_16x16x32_bf16(aF[i], bF[j], acc[i][j], 0, 0, 0);
#pragma unroll
    for (int i = 0; i < 4; ++i)
#pragma unroll
      for (int j = 0; j < 4; ++j)
        acc[i][j] = __builtin_amdgcn_mfma_f32_16x16x32_bf16(aS[i], bS[j], acc[i][j], 0, 0, 0);
    __builtin_amdgcn_s_setprio(0);

    // boundary: tile t+1 landed (issued a full tile ago). Counted, never 0 mid-loop.
    if (t < 14) {
      asm volatile("s_waitcnt vmcnt(6)" ::: "memory");
    } else if (t == 14) {
      asm volatile("s_waitcnt vmcnt(0)" ::: "memory");
    }
    __builtin_amdgcn_s_barrier();
    __builtin_amdgcn_sched_barrier(0);

    buf = (buf < 2) ? buf + 1 : 0;
  }

  // epilogue. C/D layout: col = lane&15, row = quad*4 + reg.
  const int seg = n0 >> 10;  // uniform per block
#pragma unroll
  for (int i = 0; i < 4; ++i) {
#pragma unroll
    for (int j = 0; j < 4; ++j) {
#pragma unroll
      for (int r = 0; r < 4; ++r) {
        int m = m0 + wm + i * 16 + quad * 4 + r;
        int n = n0 + wn + j * 16 + l15;
        int nn = n & 1023;
        float v = acc[i][j][r];
        if (seg == 0) {
          Cout[(size_t)m * 1024 + nn] = f2b(v);
        } else if (seg == 1) {
          (Cout + 8388608)[(size_t)m * 1024 + nn] = f2b(v);
        } else {
          int b = m >> 11, tq = m & 2047, hh = nn >> 6, d = nn & 63;
          (Cout + 16777216)[(((size_t)((b * 16 + hh) * 64 + d)) << 11) + tq] = f2b(v);
        }
      }
    }
  }
}

// ---------------- out-proj GEMM: 256x128 ring-3, hoisted reads + parity stagger ----------
// M=8192, N=1024, K=1024. Grid (32,8) = 256 blocks = exactly 1/CU, one full round, no tail.
__launch_bounds__(512, 2)
__global__ void gemm_proj(const unsigned short* __restrict__ A,
                          const unsigned short* __restrict__ Bw,
                          const float* __restrict__ bias,
                          float* __restrict__ out) {
  __shared__ unsigned short At[3][256 * 64];   // 3 x 32 KB
  __shared__ unsigned short Bt[3][128 * 64];   // 3 x 16 KB

  const int tid = threadIdx.x;
  const int lane = tid & 63;
  const int w = tid >> 6;
  const int quad = lane >> 4;
  const int l15 = lane & 15;
  const int m0 = blockIdx.x * 256;
  const int n0 = blockIdx.y * 128;
  const int wm = (w & 3) * 64;
  const int wn = (w >> 2) * 64;
  const int sf = ((w >> 2) & 1) << 2;
  const int ss = 4 - sf;

  auto stageA = [&](int buf, int kt, int c) {
    int chunk = c * 512 + tid;
    int row = chunk >> 3;
    int scol = (chunk & 7) ^ (row & 7);
    load_lds16(A + (size_t)(m0 + row) * 1024 + kt + scol * 8,
               &At[buf][(c * 512 + (w << 6)) << 3]);
  };
  auto stageB = [&](int buf, int kt, int c) {
    int chunk = c * 512 + tid;
    int row = chunk >> 3;
    int scol = (chunk & 7) ^ (row & 7);
    load_lds16(Bw + (size_t)(n0 + row) * 1024 + kt + scol * 8,
               &Bt[buf][(c * 512 + (w << 6)) << 3]);
  };

  const f32x4 z4 = {0.f, 0.f, 0.f, 0.f};
  f32x4 acc[4][4];
#pragma unroll
  for (int i = 0; i < 4; ++i)
#pragma unroll
    for (int j = 0; j < 4; ++j) acc[i][j] = z4;

#pragma unroll
  for (int c = 0; c < 4; ++c) stageA(0, 0, c);
#pragma unroll
  for (int c = 0; c < 2; ++c) stageB(0, 0, c);
#pragma unroll
  for (int c = 0; c < 4; ++c) stageA(1, 64, c);
#pragma unroll
  for (int c = 0; c < 2; ++c) stageB(1, 64, c);
  asm volatile("s_waitcnt vmcnt(6)" ::: "memory");
  __builtin_amdgcn_s_barrier();
  __builtin_amdgcn_sched_barrier(0);

  int buf = 0;
  for (int t = 0; t < 16; ++t) {
    const int sbuf = (buf >= 1) ? buf - 1 : 2;
    const int skt = (t + 2) * 64;
    const bool st = (t < 14);

    bf16x8 aF[4], bF[4], aS[4], bS[4];

#pragma unroll
    for (int i = 0; i < 4; ++i) {
      int rowA = wm + i * 16 + l15;
      aF[i] = *(const bf16x8*)&At[buf][rowA * 64 + (((sf + quad) ^ (rowA & 7)) << 3)];
    }
#pragma unroll
    for (int j = 0; j < 4; ++j) {
      int rowB = wn + j * 16 + l15;
      bF[j] = *(const bf16x8*)&Bt[buf][rowB * 64 + (((sf + quad) ^ (rowB & 7)) << 3)];
    }
    if (st) { stageA(sbuf, skt, 0); stageA(sbuf, skt, 1); stageA(sbuf, skt, 2); }
#pragma unroll
    for (int i = 0; i < 4; ++i) {
      int rowA = wm + i * 16 + l15;
      aS[i] = *(const bf16x8*)&At[buf][rowA * 64 + (((ss + quad) ^ (rowA & 7)) << 3)];
    }
#pragma unroll
    for (int j = 0; j < 4; ++j) {
      int rowB = wn + j * 16 + l15;
      bS[j] = *(const bf16x8*)&Bt[buf][rowB * 64 + (((ss + quad) ^ (rowB & 7)) << 3)];
    }
    if (st) { stageA(sbuf, skt, 3); stageB(sbuf, skt, 0); stageB(sbuf, skt, 1); }

    __builtin_amdgcn_s_setprio(1);
#pragma unroll
    for (int i = 0; i < 4; ++i)
#pragma unroll
      for (int j = 0; j < 4; ++j)
        acc[i][j] = __builtin_amdgcn_mfma_f32_16x16x32_bf16(aF[i], bF[j], acc[i][j], 0, 0, 0);
#pragma unroll
    for (int i = 0; i < 4; ++i)
#pragma unroll
      for (int j = 0; j < 4; ++j)
        acc[i][j] = __builtin_amdgcn_mfma_f32_16x16x32_bf16(aS[i], bS[j], acc[i][j], 0, 0, 0);
    __builtin_amdgcn_s_setprio(0);

    if (t < 14) {
      asm volatile("s_waitcnt vmcnt(6)" ::: "memory");
    } else if (t == 14) {
      asm volatile("s_waitcnt vmcnt(0)" ::: "memory");
    }
    __builtin_amdgcn_s_barrier();
    __builtin_amdgcn_sched_barrier(0);

    buf = (buf < 2) ? buf + 1 : 0;
  }

  // epilogue: fp32 + bias. C/D layout: col = lane&15, row = quad*4 + reg.
#pragma unroll
  for (int i = 0; i < 4; ++i)
#pragma unroll
    for (int j = 0; j < 4; ++j) {
      int n = n0 + wn + j * 16 + l15;
      float bv = bias[n];
#pragma unroll
      for (int r = 0; r < 4; ++r) {
        int m = m0 + wm + i * 16 + quad * 4 + r;
        out[(size_t)m * 1024 + n] = acc[i][j][r] + bv;
      }
    }
}

// ---------------- causal flash attention (S^T form, fixed-max softmax, QBLK=128) ---------
// R8-verified: grid (bh=64, 16) = 1024 blocks, one 128-row q-tile per block, LPT order
// (qt = 15 - blockIdx.y), 3 blocks/CU resident. XCD locality: flat%8 = bh%8.
__launch_bounds__(256, 3)
__global__ void attn_kernel(const unsigned short* __restrict__ Q,
                            const unsigned short* __restrict__ K,
                            const unsigned short* __restrict__ VT,
                            unsigned short* __restrict__ ctx) {
  __shared__ unsigned short Kt[2][64 * 64];   // 2 x 8 KB
  __shared__ unsigned short Vt[2][64 * 64];   // 2 x 8 KB
  __shared__ unsigned short Pt[128 * 64];     // 16 KB: P^T rows = block q rows (wave-local)

  const int tid = threadIdx.x;
  const int lane = tid & 63;
  const int w = tid >> 6;
  const int quad = lane >> 4;
  const int l15 = lane & 15;
  const int bh = blockIdx.x;            // head-major: keeps a head's K/V on one XCD
  const int qt = 15 - blockIdx.y;       // LPT: longest q-tiles dispatched first
  const int b = bh >> 4, h = bh & 15;

  const unsigned short* Kg = K + ((size_t)(b * 2048)) * 1024 + h * 64;  // +t*1024
  const unsigned short* Vg = VT + ((size_t)bh * 64) * 2048;             // +d*2048+t

  const float SC = 0.1803368801f;  // (1/sqrt(64)) * log2(e)
  const float M0 = 11.0f;          // fixed max in log2 domain

  const int qb = qt * 128;
  const int jn = 2 * qt + 2;           // # of 64-wide k-tiles

  // Q frags: 2 row-groups x 2 k-steps
  bf16x8 qa[2][2];
#pragma unroll
  for (int g = 0; g < 2; ++g) {
    const unsigned short* qbase =
        Q + ((size_t)(b * 2048 + qb + w * 32 + g * 16 + l15)) * 1024 + h * 64;
    qa[g][0] = *(const bf16x8*)(qbase + quad * 8);
    qa[g][1] = *(const bf16x8*)(qbase + 32 + quad * 8);
  }

  const f32x4 z4 = {0.f, 0.f, 0.f, 0.f};
  f32x4 o[2][4];
#pragma unroll
  for (int g = 0; g < 2; ++g)
#pragma unroll
    for (int nt = 0; nt < 4; ++nt) o[g][nt] = z4;
  float lrow[2] = {0.f, 0.f};

  // stage j=0 into buffer 0
#pragma unroll
  for (int c = 0; c < 2; ++c) {
    int chunk = c * 256 + tid;
    int row = chunk >> 3;
    int scol = (chunk & 7) ^ (row & 7);
    load_lds16(Kg + (size_t)row * 1024 + scol * 8, &Kt[0][((c * 256 + (w << 6)) << 3)]);
    load_lds16(Vg + ((size_t)row << 11) + scol * 8, &Vt[0][((c * 256 + (w << 6)) << 3)]);
  }

  int cur = 0;
  for (int j = 0; j < jn; ++j) {
    const int j0 = j * 64;
    __syncthreads();  // stage(j) drained; prior-iter LDS reads done

    if (j + 1 < jn) {  // prefetch j+1 into alternate buffer; overlaps compute below
      const int nj0 = j0 + 64;
#pragma unroll
      for (int c = 0; c < 2; ++c) {
        int chunk = c * 256 + tid;
        int row = chunk >> 3;
        int scol = (chunk & 7) ^ (row & 7);
        load_lds16(Kg + (size_t)(nj0 + row) * 1024 + scol * 8,
                   &Kt[cur ^ 1][((c * 256 + (w << 6)) << 3)]);
        load_lds16(Vg + ((size_t)row << 11) + nj0 + scol * 8,
                   &Vt[cur ^ 1][((c * 256 + (w << 6)) << 3)]);
      }
    }

    // S^T = K Q^T for both groups: kf read ONCE, 2 MFMA per read.
    f32x4 st[2][4];
#pragma unroll
    for (int g = 0; g < 2; ++g)
#pragma unroll
      for (int nt = 0; nt < 4; ++nt) st[g][nt] = z4;
#pragma unroll
    for (int ks = 0; ks < 2; ++ks) {
#pragma unroll
      for (int nt = 0; nt < 4; ++nt) {
        int rowK = nt * 16 + l15;
        bf16x8 kf = *(const bf16x8*)&Kt[cur][rowK * 64 + (((ks * 4 + quad) ^ (rowK & 7)) << 3)];
        st[0][nt] = __builtin_amdgcn_mfma_f32_16x16x32_bf16(kf, qa[0][ks], st[0][nt], 0, 0, 0);
        st[1][nt] = __builtin_amdgcn_mfma_f32_16x16x32_bf16(kf, qa[1][ks], st[1][nt], 0, 0, 0);
      }
    }

    // softmax: p = 2^(raw*SC - M0); causal mask; per-iter butterfly sum. Per group.
#pragma unroll
    for (int g = 0; g < 2; ++g) {
      const int qmin = qb + w * 32 + g * 16;
      const bool dg = (j0 + 63 > qmin);
      const int q = qmin + l15;
      float sum = 0.f;
#pragma unroll
      for (int nt = 0; nt < 4; ++nt) {
#pragma unroll
        for (int r = 0; r < 4; ++r) {
          float e = fmaf(st[g][nt][r], SC, -M0);
          if (dg) {
            int kpos = j0 + nt * 16 + quad * 4 + r;
            if (kpos > q) e = -1e30f;
          }
          float pv = __builtin_amdgcn_exp2f(e);
          st[g][nt][r] = pv;
          sum += pv;
        }
      }
      sum += __shfl_xor(sum, 16);
      sum += __shfl_xor(sum, 32);
      lrow[g] += sum;
    }

    // P^T -> Pt[qrow][kpos] (ushort4, swizzled by q&15), wave-local region (32 rows)
#pragma unroll
    for (int g = 0; g < 2; ++g) {
      const int qrow = w * 32 + g * 16 + l15;
#pragma unroll
      for (int nt = 0; nt < 4; ++nt) {
        ushort4 pk;
        pk.x = f2b(st[g][nt][0]); pk.y = f2b(st[g][nt][1]);
        pk.z = f2b(st[g][nt][2]); pk.w = f2b(st[g][nt][3]);
        int chunk = nt * 4 + quad;  // kpos chunk (4 shorts)
        *(ushort4*)&Pt[qrow * 64 + ((chunk ^ l15) << 2)] = pk;
      }
    }
    // no barrier: P region is wave-local

    // O += P V : vb read ONCE per (ks,nt), 2 MFMA per read.
#pragma unroll
    for (int ks = 0; ks < 2; ++ks) {
      int c0 = ks * 8 + quad * 2;
      union { ushort4 hh[2]; bf16x8 v; } pu[2];
#pragma unroll
      for (int g = 0; g < 2; ++g) {
        const int qrow = w * 32 + g * 16 + l15;
        pu[g].hh[0] = *(const ushort4*)&Pt[qrow * 64 + ((c0 ^ l15) << 2)];
        pu[g].hh[1] = *(const ushort4*)&Pt[qrow * 64 + (((c0 + 1) ^ l15) << 2)];
      }
#pragma unroll
      for (int nt = 0; nt < 4; ++nt) {
        int rowV = nt * 16 + l15;
        bf16x8 vb = *(const bf16x8*)&Vt[cur][rowV * 64 + (((ks * 4 + quad) ^ (rowV & 7)) << 3)];
        o[0][nt] = __builtin_amdgcn_mfma_f32_16x16x32_bf16(pu[0].v, vb, o[0][nt], 0, 0, 0);
        o[1][nt] = __builtin_amdgcn_mfma_f32_16x16x32_bf16(pu[1].v, vb, o[1][nt], 0, 0, 0);
      }
    }
    cur ^= 1;
  }

  // epilogue: ctx[b, q, h*64+d] bf16. O C-layout: row=q_local=quad*4+r, col=d=l15.
#pragma unroll
  for (int g = 0; g < 2; ++g) {
    float lf[4];
#pragma unroll
    for (int r = 0; r < 4; ++r) lf[r] = 1.f / __shfl(lrow[g], quad * 4 + r);
#pragma unroll
    for (int nt = 0; nt < 4; ++nt) {
#pragma unroll
      for (int r = 0; r < 4; ++r) {
        int q = qb + w * 32 + g * 16 + quad * 4 + r;
        int dcol = nt * 16 + l15;
        ctx[((size_t)(b * 2048 + q)) * 1024 + h * 64 + dcol] = f2b(o[g][nt][r] * lf[r]);
      }
    }
  }
}

// ---------------- launcher ----------------
extern "C" void kernel_launch(void* const* d_in, const int* in_sizes, int n_in,
                              void* d_out, int out_size, void* d_ws, size_t ws_size,
                              hipStream_t stream) {
  const float* x  = (const float*)d_in[0];
  // d_in[1] = mask (causal, deterministic) — unused
  const float* Wq = (const float*)d_in[2];
  const float* Wk = (const float*)d_in[3];
  const float* Wv = (const float*)d_in[4];
  const float* Wo = (const float*)d_in[5];
  const float* bo = (const float*)d_in[6];
  float* out = (float*)d_out;

  unsigned short* xb  = (unsigned short*)d_ws;      // 8.4M elems (16 MB)
  unsigned short* wb  = xb + 8388608;               // 4 x 1M elems (8 MB) — Wq,Wk,Wv,Wo contiguous
  unsigned short* Qb  = wb + 4 * 1048576;           // Q; K at +8388608, VT at +16777216
  unsigned short* Kb  = Qb + 8388608;
  unsigned short* VTb = Kb + 8388608;
  unsigned short* ctxb = xb;                        // overlay: x dead after QKV

  cast_kernel<<<6144, 256, 0, stream>>>(x, Wq, Wk, Wv, Wo, xb, wb);

  // fused QKV: N=3072 (Wq|Wk|Wv contiguous in wb), 256x128 tiles, ring-3, hoisted+stagger
  gemm_qkv<<<dim3(32, 24), 512, 0, stream>>>(xb, wb, Qb);

  // attn: grid (bh, 16) — one 128-row q-tile per block, LPT order, 1024 blocks (3/CU resident)
  attn_kernel<<<dim3(64, 16), 256, 0, stream>>>(Qb, Kb, VTb, ctxb);

  // out proj: 256x128 ring-3, grid (32,8)=256 blocks (1/CU, no tail), bias folded
  gemm_proj<<<dim3(32, 8), 512, 0, stream>>>(ctxb, wb + 3 * 1048576, bo, out);
}